// Round 3
// baseline (382.762 us; speedup 1.0000x reference)
//
#include <hip/hip_runtime.h>
#include <hip/hip_bf16.h>
#include <math.h>

#define HIDDEN 1024
#define BATCH 32
#define SEQ 2048
#define MTOT (BATCH * SEQ)   // 65536 rows

typedef __attribute__((ext_vector_type(8))) short          bf16x8;
typedef __attribute__((ext_vector_type(8))) unsigned short ushort8;
typedef __attribute__((ext_vector_type(4))) float          f32x4;

#define GLOAD_LDS16(g, l) __builtin_amdgcn_global_load_lds( \
    (const __attribute__((address_space(1))) void*)(g),      \
    (__attribute__((address_space(3))) void*)(l), 16, 0, 0)

// tanh(x) = 1 - 2/(exp2(x*2*log2e)+1); v_exp_f32 + v_rcp_f32, ~5 VALU ops.
// Saturates exactly (+/-1) via inf/0 behavior of exp2; |err| ~1e-7.
__device__ __forceinline__ float fast_tanh(float x) {
    float e = __builtin_amdgcn_exp2f(x * 2.8853900817779268f);
    return 1.0f - 2.0f * __builtin_amdgcn_rcpf(1.0f + e);
}

// ---------------------------------------------------------------------------
// fp32 -> bf16 (RNE) conversion for enc and W in ONE launch.
// ---------------------------------------------------------------------------
__global__ __launch_bounds__(256) void convert_k(
    const float* __restrict__ enc, unsigned short* __restrict__ encb,
    const float* __restrict__ W,   unsigned short* __restrict__ Wb)
{
    const int n8_enc = MTOT * (HIDDEN / 8);            // 8388608 chunks
    const int n8_tot = n8_enc + HIDDEN * (HIDDEN / 8); // + 131072
    for (int i = blockIdx.x * blockDim.x + threadIdx.x; i < n8_tot;
         i += gridDim.x * blockDim.x) {
        const float* src; unsigned short* dst; size_t idx;
        if (i < n8_enc) { src = enc; dst = encb; idx = (size_t)i; }
        else            { src = W;   dst = Wb;   idx = (size_t)(i - n8_enc); }
        float4 a = ((const float4*)src)[idx * 2];
        float4 b = ((const float4*)src)[idx * 2 + 1];
        float va[8] = {a.x, a.y, a.z, a.w, b.x, b.y, b.z, b.w};
        ushort8 r;
        #pragma unroll
        for (int j = 0; j < 8; ++j) {
            unsigned u = __float_as_uint(va[j]);
            unsigned rnd = u + 0x7FFFu + ((u >> 16) & 1u);   // RNE
            r[j] = (unsigned short)(rnd >> 16);
        }
        *(ushort8*)&dst[idx * 8] = r;
    }
}

// ---------------------------------------------------------------------------
// MFMA score GEMM (m97 structure, 128x128 tile, BK=32, 4 waves).
// XCD-grouping swizzle: all 8 n-blocks of an m-tile land on one XCD,
// temporally adjacent -> enc M-tile is fetched once into that XCD's L2.
// Epilogue: fast_tanh + packed dec/v from LDS; atomicAdd into scores.
// ---------------------------------------------------------------------------
__global__ __launch_bounds__(256) void score_gemm_mfma(
    const unsigned short* __restrict__ encb,  // [MTOT][HIDDEN] bf16
    const unsigned short* __restrict__ Wb,    // [HIDDEN][HIDDEN] bf16 (out,in)
    const float* __restrict__ dec,            // [BATCH][HIDDEN]
    const float* __restrict__ v,              // [HIDDEN]
    float* __restrict__ scores)               // [MTOT], pre-zeroed
{
    __shared__ unsigned short As[128][32];    // 8 KiB
    __shared__ unsigned short Bs[128][32];    // 8 KiB
    __shared__ float2 dvs[HIDDEN];            // 8 KiB: {dec[b,n], v[n]}

    // swizzle: xcd = bid&7 handles m-tiles [xcd*64, xcd*64+64), n fastest.
    const int bid  = blockIdx.x;
    const int xcd  = bid & 7;
    const int slot = bid >> 3;                  // 0..511
    const int mt   = xcd * 64 + (slot >> 3);    // 0..511
    const int nt   = slot & 7;                  // 0..7
    const int m0   = mt * 128;
    const int n0   = nt * 128;

    const int tid  = threadIdx.x;
    const int wid  = tid >> 6;
    const int lane = tid & 63;
    const int wm   = (wid >> 1) * 64;
    const int wn   = (wid & 1) * 64;

    const int lr = lane & 15;            // frag row/col
    const int kb = (lane >> 4) * 8;      // frag k-offset (bf16 elems)

    // preload packed dec/v (b is block-uniform: 2048 rows per batch, 128|2048)
    const int b = m0 >> 11;
    #pragma unroll
    for (int j = 0; j < 4; ++j) {
        const int n = tid * 4 + j;
        dvs[n] = make_float2(dec[b * HIDDEN + n], v[n]);
    }

    f32x4 acc[4][4] = {};

    for (int k0 = 0; k0 < HIDDEN; k0 += 32) {
        __syncthreads();   // previous tile's LDS reads done (also fences dvs)
        #pragma unroll
        for (int c = 0; c < 2; ++c) {
            const int chw  = c * 256 + wid * 64;       // wave-uniform chunk base
            const int ch   = chw + lane;               // per-lane chunk
            const int row  = ch >> 2, kh = (ch & 3) * 8;
            GLOAD_LDS16(&encb[(size_t)(m0 + row) * HIDDEN + k0 + kh],
                        (char*)&As[0][0] + chw * 16);
            GLOAD_LDS16(&Wb  [(size_t)(n0 + row) * HIDDEN + k0 + kh],
                        (char*)&Bs[0][0] + chw * 16);
        }
        __syncthreads();   // drains vmcnt(0): tile resident

        bf16x8 af[4], bf[4];
        #pragma unroll
        for (int f = 0; f < 4; ++f)
            af[f] = *(const bf16x8*)&As[wm + f * 16 + lr][kb];
        #pragma unroll
        for (int f = 0; f < 4; ++f)
            bf[f] = *(const bf16x8*)&Bs[wn + f * 16 + lr][kb];
        #pragma unroll
        for (int i = 0; i < 4; ++i)
            #pragma unroll
            for (int j = 0; j < 4; ++j)
                acc[i][j] = __builtin_amdgcn_mfma_f32_16x16x32_bf16(
                    af[i], bf[j], acc[i][j], 0, 0, 0);
    }

    // Epilogue. C/D layout: col = lane&15, row = (lane>>4)*4 + reg.
    const int rowgrp = lane >> 4;
    const int col    = lane & 15;

    float2 dv[4];
    #pragma unroll
    for (int fj = 0; fj < 4; ++fj)
        dv[fj] = dvs[n0 + wn + fj * 16 + col];

    #pragma unroll
    for (int fi = 0; fi < 4; ++fi) {
        #pragma unroll
        for (int r = 0; r < 4; ++r) {
            const int m = m0 + wm + fi * 16 + rowgrp * 4 + r;
            float rp = 0.f;
            #pragma unroll
            for (int fj = 0; fj < 4; ++fj) {
                float t = fast_tanh(acc[fi][fj][r] + dv[fj].x);
                rp = fmaf(t, dv[fj].y, rp);
            }
            rp += __shfl_xor(rp, 1, 64);
            rp += __shfl_xor(rp, 2, 64);
            rp += __shfl_xor(rp, 4, 64);
            rp += __shfl_xor(rp, 8, 64);
            if (col == 0) atomicAdd(&scores[m], rp);
        }
    }
}

// ---------------------------------------------------------------------------
// softmax over SEQ per batch. One 256-thread block per batch row.
// ---------------------------------------------------------------------------
__global__ __launch_bounds__(256) void softmax_k(
    const float* __restrict__ scores, float* __restrict__ wts)
{
    __shared__ float redmax[4];
    __shared__ float redsum[4];
    const int b = blockIdx.x;
    const int tid = threadIdx.x;
    const float* row = scores + b * SEQ;

    float vals[8];
    float lmax = -1e30f;
    #pragma unroll
    for (int j = 0; j < 8; ++j) {
        vals[j] = row[tid + j * 256];
        lmax = fmaxf(lmax, vals[j]);
    }
    #pragma unroll
    for (int off = 1; off < 64; off <<= 1)
        lmax = fmaxf(lmax, __shfl_xor(lmax, off, 64));
    if ((tid & 63) == 0) redmax[tid >> 6] = lmax;
    __syncthreads();
    const float gmax = fmaxf(fmaxf(redmax[0], redmax[1]),
                             fmaxf(redmax[2], redmax[3]));

    float lsum = 0.f;
    #pragma unroll
    for (int j = 0; j < 8; ++j) {
        vals[j] = expf(vals[j] - gmax);
        lsum += vals[j];
    }
    #pragma unroll
    for (int off = 1; off < 64; off <<= 1)
        lsum += __shfl_xor(lsum, off, 64);
    if ((tid & 63) == 0) redsum[tid >> 6] = lsum;
    __syncthreads();
    const float inv = 1.f / (redsum[0] + redsum[1] + redsum[2] + redsum[3]);

    #pragma unroll
    for (int j = 0; j < 8; ++j)
        wts[b * SEQ + tid + j * 256] = vals[j] * inv;
}

// ---------------------------------------------------------------------------
// context[b,h] = sum_s w[b,s] * enc[b,s,h], reading the bf16 enc copy.
// ---------------------------------------------------------------------------
__global__ __launch_bounds__(256) void context_bf16_k(
    const unsigned short* __restrict__ encb,
    const float* __restrict__ w,
    float* __restrict__ ctx)
{
    const int b     = blockIdx.x >> 3;
    const int chunk = blockIdx.x & 7;
    const int sOff  = threadIdx.x >> 4;
    const int hg    = threadIdx.x & 15;
    const int h     = chunk * 128 + hg * 8;

    float acc[8] = {};
    for (int s = sOff; s < SEQ; s += 16) {
        const float ws = w[b * SEQ + s];
        ushort8 e = *(const ushort8*)&encb[(size_t)(b * SEQ + s) * HIDDEN + h];
        #pragma unroll
        for (int j = 0; j < 8; ++j)
            acc[j] = fmaf(ws, __uint_as_float((unsigned)e[j] << 16), acc[j]);
    }
    __shared__ float red[16][128];
    #pragma unroll
    for (int j = 0; j < 8; ++j) red[sOff][hg * 8 + j] = acc[j];
    __syncthreads();
    if (threadIdx.x < 128) {
        float r = 0.f;
        #pragma unroll
        for (int g = 0; g < 16; ++g) r += red[g][threadIdx.x];
        ctx[b * HIDDEN + chunk * 128 + threadIdx.x] = r;
    }
}

// ---------------------------------------------------------------------------
// Fallback fp32 path, used only if ws_size is too small.
// ---------------------------------------------------------------------------
__global__ __launch_bounds__(256) void score_gemm_f32(
    const float* __restrict__ enc, const float* __restrict__ W,
    const float* __restrict__ dec, const float* __restrict__ v,
    float* __restrict__ scores)
{
    __shared__ float As[16][64 + 1];
    __shared__ float Bs[16][64 + 1];
    const int tid = threadIdx.x;
    const int m0 = (blockIdx.x >> 4) * 64;
    const int n0 = (blockIdx.x & 15) * 64;
    const int ty = tid >> 4, tx = tid & 15;
    const int lr = tid >> 2, lc = tid & 3;
    float acc[4][4] = {};
    for (int k0 = 0; k0 < HIDDEN; k0 += 16) {
        float4 a = *(const float4*)&enc[(size_t)(m0 + lr) * HIDDEN + k0 + lc * 4];
        float4 b = *(const float4*)&W  [(size_t)(n0 + lr) * HIDDEN + k0 + lc * 4];
        __syncthreads();
        As[lc*4+0][lr]=a.x; As[lc*4+1][lr]=a.y; As[lc*4+2][lr]=a.z; As[lc*4+3][lr]=a.w;
        Bs[lc*4+0][lr]=b.x; Bs[lc*4+1][lr]=b.y; Bs[lc*4+2][lr]=b.z; Bs[lc*4+3][lr]=b.w;
        __syncthreads();
        #pragma unroll
        for (int k = 0; k < 16; ++k) {
            float4 av = *(const float4*)&As[k][ty * 4];
            float4 bv = *(const float4*)&Bs[k][tx * 4];
            float aa[4] = {av.x, av.y, av.z, av.w};
            float bb[4] = {bv.x, bv.y, bv.z, bv.w};
            #pragma unroll
            for (int i = 0; i < 4; ++i)
                #pragma unroll
                for (int j = 0; j < 4; ++j)
                    acc[i][j] = fmaf(aa[i], bb[j], acc[i][j]);
        }
    }
    float rowpart[4];
    #pragma unroll
    for (int i = 0; i < 4; ++i) {
        const int m = m0 + ty * 4 + i;
        const int b = m >> 11;
        float rp = 0.f;
        #pragma unroll
        for (int j = 0; j < 4; ++j) {
            const int n = n0 + tx * 4 + j;
            rp = fmaf(fast_tanh(acc[i][j] + dec[b * HIDDEN + n]), v[n], rp);
        }
        rowpart[i] = rp;
    }
    #pragma unroll
    for (int off = 1; off <= 8; off <<= 1)
        #pragma unroll
        for (int i = 0; i < 4; ++i)
            rowpart[i] += __shfl_xor(rowpart[i], off, 64);
    if (tx == 0)
        #pragma unroll
        for (int i = 0; i < 4; ++i)
            atomicAdd(&scores[m0 + ty * 4 + i], rowpart[i]);
}

__global__ __launch_bounds__(256) void context_f32_k(
    const float* __restrict__ enc, const float* __restrict__ w,
    float* __restrict__ ctx)
{
    const int b = blockIdx.x >> 3, chunk = blockIdx.x & 7;
    const int sOff = threadIdx.x >> 6, hp = threadIdx.x & 63;
    const int h = chunk * 128 + hp * 2;
    float2 acc = {0.f, 0.f};
    for (int s = sOff; s < SEQ; s += 4) {
        const float ws = w[b * SEQ + s];
        const float2 e = *(const float2*)&enc[(size_t)(b * SEQ + s) * HIDDEN + h];
        acc.x = fmaf(ws, e.x, acc.x);
        acc.y = fmaf(ws, e.y, acc.y);
    }
    __shared__ float2 red[4][64];
    red[sOff][hp] = acc;
    __syncthreads();
    if (sOff == 0) {
        float2 r = red[0][hp];
        #pragma unroll
        for (int t = 1; t < 4; ++t) { r.x += red[t][hp].x; r.y += red[t][hp].y; }
        ctx[b * HIDDEN + h] = r.x;
        ctx[b * HIDDEN + h + 1] = r.y;
    }
}

// ---------------------------------------------------------------------------
extern "C" void kernel_launch(void* const* d_in, const int* in_sizes, int n_in,
                              void* d_out, int out_size, void* d_ws, size_t ws_size,
                              hipStream_t stream) {
    const float* dec = (const float*)d_in[0];   // [32, 1024]
    const float* enc = (const float*)d_in[1];   // [32, 2048, 1024]
    const float* W   = (const float*)d_in[2];   // [1024, 1024]
    const float* v   = (const float*)d_in[3];   // [1, 1024]

    float* out = (float*)d_out;
    float* ctx = out;                           // [32, 1024]
    float* wts = out + BATCH * HIDDEN;          // [32, 2048]

    const size_t scores_bytes = (size_t)MTOT * sizeof(float);          // 256 KiB
    const size_t encb_bytes   = (size_t)MTOT * HIDDEN * 2;             // 128 MiB
    const size_t wb_bytes     = (size_t)HIDDEN * HIDDEN * 2;           // 2 MiB
    const size_t needed = scores_bytes + encb_bytes + wb_bytes;

    float* scores = (float*)d_ws;

    if (ws_size >= needed) {
        unsigned short* encb = (unsigned short*)((char*)d_ws + scores_bytes);
        unsigned short* Wb   = (unsigned short*)((char*)d_ws + scores_bytes + encb_bytes);

        hipMemsetAsync(scores, 0, scores_bytes, stream);
        convert_k<<<dim3(2048), dim3(256), 0, stream>>>(enc, encb, W, Wb);
        score_gemm_mfma<<<dim3(4096), dim3(256), 0, stream>>>(encb, Wb, dec, v, scores);
        softmax_k<<<dim3(BATCH), dim3(256), 0, stream>>>(scores, wts);
        context_bf16_k<<<dim3(BATCH * 8), dim3(256), 0, stream>>>(encb, wts, ctx);
    } else {
        hipMemsetAsync(scores, 0, scores_bytes, stream);
        score_gemm_f32<<<dim3(16384), dim3(256), 0, stream>>>(enc, W, dec, v, scores);
        softmax_k<<<dim3(BATCH), dim3(256), 0, stream>>>(scores, wts);
        context_f32_k<<<dim3(BATCH * 8), dim3(256), 0, stream>>>(enc, wts, ctx);
    }
}

// Round 5
// 305.554 us; speedup vs baseline: 1.2527x; 1.2527x over previous
//
#include <hip/hip_runtime.h>
#include <hip/hip_bf16.h>
#include <math.h>

#define HIDDEN 1024
#define BATCH 32
#define SEQ 2048
#define MTOT (BATCH * SEQ)   // 65536 rows
#define N_PLANES 16          // 8 n-tiles x 2 n-half waves

typedef __attribute__((ext_vector_type(8))) short          bf16x8;
typedef __attribute__((ext_vector_type(8))) unsigned short ushort8;
typedef __attribute__((ext_vector_type(4))) float          f32x4;

#define GLOAD_LDS16(g, l) __builtin_amdgcn_global_load_lds( \
    (const __attribute__((address_space(1))) void*)(g),      \
    (__attribute__((address_space(3))) void*)(l), 16, 0, 0)

// tanh(x) = 1 - 2/(exp2(x*2*log2e)+1); saturates exactly via exp2 inf/0.
__device__ __forceinline__ float fast_tanh(float x) {
    float e = __builtin_amdgcn_exp2f(x * 2.8853900817779268f);
    return 1.0f - 2.0f * __builtin_amdgcn_rcpf(1.0f + e);
}

// ---------------------------------------------------------------------------
// fp32 -> bf16 (RNE) conversion for enc and W in ONE launch.
// ---------------------------------------------------------------------------
__global__ __launch_bounds__(256) void convert_k(
    const float* __restrict__ enc, unsigned short* __restrict__ encb,
    const float* __restrict__ W,   unsigned short* __restrict__ Wb)
{
    const int n8_enc = MTOT * (HIDDEN / 8);
    const int n8_tot = n8_enc + HIDDEN * (HIDDEN / 8);
    for (int i = blockIdx.x * blockDim.x + threadIdx.x; i < n8_tot;
         i += gridDim.x * blockDim.x) {
        const float* src; unsigned short* dst; size_t idx;
        if (i < n8_enc) { src = enc; dst = encb; idx = (size_t)i; }
        else            { src = W;   dst = Wb;   idx = (size_t)(i - n8_enc); }
        float4 a = ((const float4*)src)[idx * 2];
        float4 b = ((const float4*)src)[idx * 2 + 1];
        float va[8] = {a.x, a.y, a.z, a.w, b.x, b.y, b.z, b.w};
        ushort8 r;
        #pragma unroll
        for (int j = 0; j < 8; ++j) {
            unsigned u = __float_as_uint(va[j]);
            unsigned rnd = u + 0x7FFFu + ((u >> 16) & 1u);   // RNE
            r[j] = (unsigned short)(rnd >> 16);
        }
        *(ushort8*)&dst[idx * 8] = r;
    }
}

// ---------------------------------------------------------------------------
// MFMA score GEMM: 128x128 tile, BK=32, 4 waves, 2-phase double-buffered
// pipeline (stage t+1 issued before compute t; ONE __syncthreads per K-step
// whose implicit vmcnt(0)+lgkmcnt(0) drain completes the prefetch AND
// protects the buffer being re-staged next iteration).
// PARTIALS=true : each WAVE stores its 64-col partials to its own plane
//                 partial[(nt*2 + (wid&1))*MTOT + m]  — no races, no memset.
// PARTIALS=false: legacy atomicAdd into scores[] (pre-zeroed).
// ---------------------------------------------------------------------------
template <bool PARTIALS>
__global__ __launch_bounds__(256) void score_gemm_mfma(
    const unsigned short* __restrict__ encb,  // [MTOT][HIDDEN] bf16
    const unsigned short* __restrict__ Wb,    // [HIDDEN][HIDDEN] bf16 (out,in)
    const float* __restrict__ dec,            // [BATCH][HIDDEN]
    const float* __restrict__ v,              // [HIDDEN]
    float* __restrict__ outp)                 // partial[16][MTOT] or scores[MTOT]
{
    __shared__ unsigned short As[2][128][32];   // 16 KiB
    __shared__ unsigned short Bs[2][128][32];   // 16 KiB

    // XCD-grouping swizzle (bijective, 4096 % 8 == 0): xcd = bid&7 owns
    // m-tiles [xcd*64, xcd*64+64), nt fastest -> enc tile L2-resident.
    const int bid  = blockIdx.x;
    const int xcd  = bid & 7;
    const int slot = bid >> 3;                  // 0..511
    const int mt   = xcd * 64 + (slot >> 3);    // 0..511
    const int nt   = slot & 7;                  // 0..7
    const int m0   = mt * 128;
    const int n0   = nt * 128;

    const int tid  = threadIdx.x;
    const int wid  = tid >> 6;
    const int lane = tid & 63;
    const int wm   = (wid >> 1) * 64;
    const int wn   = (wid & 1) * 64;

    const int lr = lane & 15;            // frag row/col
    const int kb = (lane >> 4) * 8;      // frag k-offset (bf16 elems)

    auto stage = [&](int buf, int k0) {
        #pragma unroll
        for (int c = 0; c < 2; ++c) {
            const int chw = c * 256 + wid * 64;        // wave-uniform chunk base
            const int ch  = chw + lane;
            const int row = ch >> 2, kh = (ch & 3) * 8;
            GLOAD_LDS16(&encb[(size_t)(m0 + row) * HIDDEN + k0 + kh],
                        (char*)&As[buf][0][0] + (size_t)chw * 16);
            GLOAD_LDS16(&Wb  [(size_t)(n0 + row) * HIDDEN + k0 + kh],
                        (char*)&Bs[buf][0][0] + (size_t)chw * 16);
        }
    };

    stage(0, 0);
    __syncthreads();                     // vmcnt(0) drain: buf0 resident

    f32x4 acc[4][4] = {};
    int cur = 0;
    #pragma unroll 1
    for (int t = 0; t < HIDDEN / 32; ++t) {
        if (t + 1 < HIDDEN / 32) stage(cur ^ 1, (t + 1) * 32);  // prefetch

        bf16x8 af[4], bf[4];
        #pragma unroll
        for (int f = 0; f < 4; ++f)
            af[f] = *(const bf16x8*)&As[cur][wm + f * 16 + lr][kb];
        #pragma unroll
        for (int f = 0; f < 4; ++f)
            bf[f] = *(const bf16x8*)&Bs[cur][wn + f * 16 + lr][kb];
        #pragma unroll
        for (int i = 0; i < 4; ++i)
            #pragma unroll
            for (int j = 0; j < 4; ++j)
                acc[i][j] = __builtin_amdgcn_mfma_f32_16x16x32_bf16(
                    af[i], bf[j], acc[i][j], 0, 0, 0);

        if (t + 1 < HIDDEN / 32) {
            __syncthreads();             // next tile resident; cur reads done
            cur ^= 1;
        }
    }

    // Epilogue. C/D layout: col = lane&15, row = (lane>>4)*4 + reg.
    const int rowgrp = lane >> 4;
    const int col    = lane & 15;
    const int b      = m0 >> 11;                 // batch (block-uniform)
    const float* decb = dec + b * HIDDEN;

    float2 dv[4];
    #pragma unroll
    for (int fj = 0; fj < 4; ++fj) {
        const int n = n0 + wn + fj * 16 + col;
        dv[fj] = make_float2(decb[n], v[n]);
    }

    const size_t plane = (size_t)(nt * 2 + (wid & 1)) * MTOT;  // per-wave plane

    #pragma unroll
    for (int fi = 0; fi < 4; ++fi) {
        #pragma unroll
        for (int r = 0; r < 4; ++r) {
            const int m = m0 + wm + fi * 16 + rowgrp * 4 + r;
            float rp = 0.f;
            #pragma unroll
            for (int fj = 0; fj < 4; ++fj) {
                float t = fast_tanh(acc[fi][fj][r] + dv[fj].x);
                rp = fmaf(t, dv[fj].y, rp);
            }
            rp += __shfl_xor(rp, 1, 64);
            rp += __shfl_xor(rp, 2, 64);
            rp += __shfl_xor(rp, 4, 64);
            rp += __shfl_xor(rp, 8, 64);
            if (col == 0) {
                if (PARTIALS) outp[plane + m] = rp;   // wave-private plane
                else          atomicAdd(&outp[m], rp);
            }
        }
    }
}

// ---------------------------------------------------------------------------
// softmax over SEQ per batch. PARTIALS: sum 16 partial score planes first.
// ---------------------------------------------------------------------------
template <bool PARTIALS>
__global__ __launch_bounds__(256) void softmax_k(
    const float* __restrict__ scores, float* __restrict__ wts)
{
    __shared__ float redmax[4];
    __shared__ float redsum[4];
    const int b = blockIdx.x;
    const int tid = threadIdx.x;

    float vals[8];
    float lmax = -1e30f;
    #pragma unroll
    for (int j = 0; j < 8; ++j) {
        const int idx = b * SEQ + tid + j * 256;
        float s;
        if (PARTIALS) {
            s = 0.f;
            #pragma unroll
            for (int p = 0; p < N_PLANES; ++p)
                s += scores[(size_t)p * MTOT + idx];
        } else {
            s = scores[idx];
        }
        vals[j] = s;
        lmax = fmaxf(lmax, s);
    }
    #pragma unroll
    for (int off = 1; off < 64; off <<= 1)
        lmax = fmaxf(lmax, __shfl_xor(lmax, off, 64));
    if ((tid & 63) == 0) redmax[tid >> 6] = lmax;
    __syncthreads();
    const float gmax = fmaxf(fmaxf(redmax[0], redmax[1]),
                             fmaxf(redmax[2], redmax[3]));

    float lsum = 0.f;
    #pragma unroll
    for (int j = 0; j < 8; ++j) {
        vals[j] = expf(vals[j] - gmax);
        lsum += vals[j];
    }
    #pragma unroll
    for (int off = 1; off < 64; off <<= 1)
        lsum += __shfl_xor(lsum, off, 64);
    if ((tid & 63) == 0) redsum[tid >> 6] = lsum;
    __syncthreads();
    const float inv = 1.f / (redsum[0] + redsum[1] + redsum[2] + redsum[3]);

    #pragma unroll
    for (int j = 0; j < 8; ++j)
        wts[b * SEQ + tid + j * 256] = vals[j] * inv;
}

// ---------------------------------------------------------------------------
// context[b,h] = sum_s w[b,s] * enc[b,s,h], reading the bf16 enc copy.
// ---------------------------------------------------------------------------
__global__ __launch_bounds__(256) void context_bf16_k(
    const unsigned short* __restrict__ encb,
    const float* __restrict__ w,
    float* __restrict__ ctx)
{
    const int b     = blockIdx.x >> 3;
    const int chunk = blockIdx.x & 7;
    const int sOff  = threadIdx.x >> 4;
    const int hg    = threadIdx.x & 15;
    const int h     = chunk * 128 + hg * 8;

    float acc[8] = {};
    for (int s = sOff; s < SEQ; s += 16) {
        const float ws = w[b * SEQ + s];
        ushort8 e = *(const ushort8*)&encb[(size_t)(b * SEQ + s) * HIDDEN + h];
        #pragma unroll
        for (int j = 0; j < 8; ++j)
            acc[j] = fmaf(ws, __uint_as_float((unsigned)e[j] << 16), acc[j]);
    }
    __shared__ float red[16][128];
    #pragma unroll
    for (int j = 0; j < 8; ++j) red[sOff][hg * 8 + j] = acc[j];
    __syncthreads();
    if (threadIdx.x < 128) {
        float r = 0.f;
        #pragma unroll
        for (int g = 0; g < 16; ++g) r += red[g][threadIdx.x];
        ctx[b * HIDDEN + chunk * 128 + threadIdx.x] = r;
    }
}

// ---------------------------------------------------------------------------
// Fallback fp32 path, used only if ws_size is too small for bf16 copies.
// ---------------------------------------------------------------------------
__global__ __launch_bounds__(256) void score_gemm_f32(
    const float* __restrict__ enc, const float* __restrict__ W,
    const float* __restrict__ dec, const float* __restrict__ v,
    float* __restrict__ scores)
{
    __shared__ float As[16][64 + 1];
    __shared__ float Bs[16][64 + 1];
    const int tid = threadIdx.x;
    const int m0 = (blockIdx.x >> 4) * 64;
    const int n0 = (blockIdx.x & 15) * 64;
    const int ty = tid >> 4, tx = tid & 15;
    const int lr = tid >> 2, lc = tid & 3;
    float acc[4][4] = {};
    for (int k0 = 0; k0 < HIDDEN; k0 += 16) {
        float4 a = *(const float4*)&enc[(size_t)(m0 + lr) * HIDDEN + k0 + lc * 4];
        float4 b = *(const float4*)&W  [(size_t)(n0 + lr) * HIDDEN + k0 + lc * 4];
        __syncthreads();
        As[lc*4+0][lr]=a.x; As[lc*4+1][lr]=a.y; As[lc*4+2][lr]=a.z; As[lc*4+3][lr]=a.w;
        Bs[lc*4+0][lr]=b.x; Bs[lc*4+1][lr]=b.y; Bs[lc*4+2][lr]=b.z; Bs[lc*4+3][lr]=b.w;
        __syncthreads();
        #pragma unroll
        for (int k = 0; k < 16; ++k) {
            float4 av = *(const float4*)&As[k][ty * 4];
            float4 bv = *(const float4*)&Bs[k][tx * 4];
            float aa[4] = {av.x, av.y, av.z, av.w};
            float bb[4] = {bv.x, bv.y, bv.z, bv.w};
            #pragma unroll
            for (int i = 0; i < 4; ++i)
                #pragma unroll
                for (int j = 0; j < 4; ++j)
                    acc[i][j] = fmaf(aa[i], bb[j], acc[i][j]);
        }
    }
    float rowpart[4];
    #pragma unroll
    for (int i = 0; i < 4; ++i) {
        const int m = m0 + ty * 4 + i;
        const int b = m >> 11;
        float rp = 0.f;
        #pragma unroll
        for (int j = 0; j < 4; ++j) {
            const int n = n0 + tx * 4 + j;
            rp = fmaf(fast_tanh(acc[i][j] + dec[b * HIDDEN + n]), v[n], rp);
        }
        rowpart[i] = rp;
    }
    #pragma unroll
    for (int off = 1; off <= 8; off <<= 1)
        #pragma unroll
        for (int i = 0; i < 4; ++i)
            rowpart[i] += __shfl_xor(rowpart[i], off, 64);
    if (tx == 0)
        #pragma unroll
        for (int i = 0; i < 4; ++i)
            atomicAdd(&scores[m0 + ty * 4 + i], rowpart[i]);
}

__global__ __launch_bounds__(256) void context_f32_k(
    const float* __restrict__ enc, const float* __restrict__ w,
    float* __restrict__ ctx)
{
    const int b = blockIdx.x >> 3, chunk = blockIdx.x & 7;
    const int sOff = threadIdx.x >> 6, hp = threadIdx.x & 63;
    const int h = chunk * 128 + hp * 2;
    float2 acc = {0.f, 0.f};
    for (int s = sOff; s < SEQ; s += 4) {
        const float ws = w[b * SEQ + s];
        const float2 e = *(const float2*)&enc[(size_t)(b * SEQ + s) * HIDDEN + h];
        acc.x = fmaf(ws, e.x, acc.x);
        acc.y = fmaf(ws, e.y, acc.y);
    }
    __shared__ float2 red[4][64];
    red[sOff][hp] = acc;
    __syncthreads();
    if (sOff == 0) {
        float2 r = red[0][hp];
        #pragma unroll
        for (int t = 1; t < 4; ++t) { r.x += red[t][hp].x; r.y += red[t][hp].y; }
        ctx[b * HIDDEN + h] = r.x;
        ctx[b * HIDDEN + h + 1] = r.y;
    }
}

// ---------------------------------------------------------------------------
extern "C" void kernel_launch(void* const* d_in, const int* in_sizes, int n_in,
                              void* d_out, int out_size, void* d_ws, size_t ws_size,
                              hipStream_t stream) {
    const float* dec = (const float*)d_in[0];   // [32, 1024]
    const float* enc = (const float*)d_in[1];   // [32, 2048, 1024]
    const float* W   = (const float*)d_in[2];   // [1024, 1024]
    const float* v   = (const float*)d_in[3];   // [1, 1024]

    float* out = (float*)d_out;
    float* ctx = out;                           // [32, 1024]
    float* wts = out + BATCH * HIDDEN;          // [32, 2048]

    const size_t part_bytes   = (size_t)N_PLANES * MTOT * sizeof(float); // 4 MiB
    const size_t scores_bytes = (size_t)MTOT * sizeof(float);            // 256 KiB
    const size_t encb_bytes   = (size_t)MTOT * HIDDEN * 2;               // 128 MiB
    const size_t wb_bytes     = (size_t)HIDDEN * HIDDEN * 2;             // 2 MiB

    const size_t need_part   = part_bytes + encb_bytes + wb_bytes;
    const size_t need_atomic = scores_bytes + encb_bytes + wb_bytes;

    if (ws_size >= need_part) {
        float* partial = (float*)d_ws;
        unsigned short* encb = (unsigned short*)((char*)d_ws + part_bytes);
        unsigned short* Wb   = (unsigned short*)((char*)d_ws + part_bytes + encb_bytes);

        convert_k<<<dim3(2048), dim3(256), 0, stream>>>(enc, encb, W, Wb);
        score_gemm_mfma<true><<<dim3(4096), dim3(256), 0, stream>>>(encb, Wb, dec, v, partial);
        softmax_k<true><<<dim3(BATCH), dim3(256), 0, stream>>>(partial, wts);
        context_bf16_k<<<dim3(BATCH * 8), dim3(256), 0, stream>>>(encb, wts, ctx);
    } else if (ws_size >= need_atomic) {
        float* scores = (float*)d_ws;
        unsigned short* encb = (unsigned short*)((char*)d_ws + scores_bytes);
        unsigned short* Wb   = (unsigned short*)((char*)d_ws + scores_bytes + encb_bytes);

        hipMemsetAsync(scores, 0, scores_bytes, stream);
        convert_k<<<dim3(2048), dim3(256), 0, stream>>>(enc, encb, W, Wb);
        score_gemm_mfma<false><<<dim3(4096), dim3(256), 0, stream>>>(encb, Wb, dec, v, scores);
        softmax_k<false><<<dim3(BATCH), dim3(256), 0, stream>>>(scores, wts);
        context_bf16_k<<<dim3(BATCH * 8), dim3(256), 0, stream>>>(encb, wts, ctx);
    } else {
        float* scores = (float*)d_ws;
        hipMemsetAsync(scores, 0, scores_bytes, stream);
        score_gemm_f32<<<dim3(16384), dim3(256), 0, stream>>>(enc, W, dec, v, scores);
        softmax_k<false><<<dim3(BATCH), dim3(256), 0, stream>>>(scores, wts);
        context_f32_k<<<dim3(BATCH * 8), dim3(256), 0, stream>>>(enc, wts, ctx);
    }
}

// Round 6
// 281.808 us; speedup vs baseline: 1.3582x; 1.0843x over previous
//
#include <hip/hip_runtime.h>
#include <hip/hip_bf16.h>
#include <math.h>

#define HIDDEN 1024
#define BATCH 32
#define SEQ 2048
#define MTOT (BATCH * SEQ)   // 65536 rows
#define N_PLANES 8           // 4 n-tiles x 2 wn-waves

#define BM 128
#define BN 256
#define BK 32
#define NKS (HIDDEN / BK)    // 32 K-steps

typedef __attribute__((ext_vector_type(8))) short          bf16x8;
typedef __attribute__((ext_vector_type(8))) unsigned short ushort8;
typedef __attribute__((ext_vector_type(4))) float          f32x4;

#define GLOAD_LDS16(g, l) __builtin_amdgcn_global_load_lds( \
    (const __attribute__((address_space(1))) void*)(g),      \
    (__attribute__((address_space(3))) void*)(l), 16, 0, 0)

// tanh(x) = 1 - 2/(exp2(x*2*log2e)+1); saturates exactly via exp2 inf/0.
__device__ __forceinline__ float fast_tanh(float x) {
    float e = __builtin_amdgcn_exp2f(x * 2.8853900817779268f);
    return 1.0f - 2.0f * __builtin_amdgcn_rcpf(1.0f + e);
}

// ---------------------------------------------------------------------------
// fp32 -> bf16 (RNE) conversion for enc and W in ONE launch.
// ---------------------------------------------------------------------------
__global__ __launch_bounds__(256) void convert_k(
    const float* __restrict__ enc, unsigned short* __restrict__ encb,
    const float* __restrict__ W,   unsigned short* __restrict__ Wb)
{
    const int n8_enc = MTOT * (HIDDEN / 8);
    const int n8_tot = n8_enc + HIDDEN * (HIDDEN / 8);
    for (int i = blockIdx.x * blockDim.x + threadIdx.x; i < n8_tot;
         i += gridDim.x * blockDim.x) {
        const float* src; unsigned short* dst; size_t idx;
        if (i < n8_enc) { src = enc; dst = encb; idx = (size_t)i; }
        else            { src = W;   dst = Wb;   idx = (size_t)(i - n8_enc); }
        float4 a = ((const float4*)src)[idx * 2];
        float4 b = ((const float4*)src)[idx * 2 + 1];
        float va[8] = {a.x, a.y, a.z, a.w, b.x, b.y, b.z, b.w};
        ushort8 r;
        #pragma unroll
        for (int j = 0; j < 8; ++j) {
            unsigned u = __float_as_uint(va[j]);
            unsigned rnd = u + 0x7FFFu + ((u >> 16) & 1u);   // RNE
            r[j] = (unsigned short)(rnd >> 16);
        }
        *(ushort8*)&dst[idx * 8] = r;
    }
}

// ---------------------------------------------------------------------------
// MFMA score GEMM: BM=128 x BN=256 tile, BK=32, 4 waves (wave tile 64x128:
// 12 ds_read_b128 feed 32 MFMAs). 3-buffer LDS rotation with COUNTED vmcnt:
//   prologue: stage(0), stage(1), vmcnt(6), barrier
//   step t:   stage((t+2)%3) | ds_read buf t%3 | 32 MFMA |
//             lgkmcnt(0) ; vmcnt(6 steady / 0 tail) ; s_barrier
// Ledger: at step-t end, outstanding = buf(t+1) 6 + buf(t+2) 6 loads;
// vmcnt(6) retires the oldest 6 -> buf(t+1) resident; barrier publishes it.
// Buf t%3 is re-staged only at t+1, after lgkmcnt(0)+barrier prove all
// waves' reads of it completed. Never vmcnt(0) in steady state (T4).
// PARTIALS=true : wave-private planes partial[(nt*2+(wid&1))*MTOT + m].
// PARTIALS=false: atomicAdd into scores[] (pre-zeroed).
// ---------------------------------------------------------------------------
template <bool PARTIALS>
__global__ __launch_bounds__(256, 2) void score_gemm_mfma(
    const unsigned short* __restrict__ encb,  // [MTOT][HIDDEN] bf16
    const unsigned short* __restrict__ Wb,    // [HIDDEN][HIDDEN] bf16 (out,in)
    const float* __restrict__ dec,            // [BATCH][HIDDEN]
    const float* __restrict__ v,              // [HIDDEN]
    float* __restrict__ outp)                 // partial[8][MTOT] or scores[MTOT]
{
    __shared__ unsigned short As[3][BM][BK];   // 24 KiB
    __shared__ unsigned short Bs[3][BN][BK];   // 48 KiB

    // XCD-grouping swizzle (bijective: 2048 blocks, 8 xcds, 256 slots each):
    // xcd owns m-tiles [xcd*64, xcd*64+64), nt fastest -> enc tile L2-local.
    const int bid  = blockIdx.x;
    const int xcd  = bid & 7;
    const int slot = bid >> 3;                 // 0..255
    const int mt   = xcd * 64 + (slot >> 2);   // 0..511
    const int nt   = slot & 3;                 // 0..3
    const int m0   = mt * BM;
    const int n0   = nt * BN;

    const int tid  = threadIdx.x;
    const int wid  = tid >> 6;
    const int lane = tid & 63;
    const int wm   = (wid >> 1) * 64;          // 0 / 64
    const int wn   = (wid & 1) * 128;          // 0 / 128

    const int lr = lane & 15;                  // frag row/col
    const int kb = (lane >> 4) * 8;            // frag k-offset (bf16 elems)

    // stage A(128x32) + B(256x32) for k-offset k0 into buffer `buf`.
    // 6 gload_lds per thread (2 A + 4 B); LDS dest linear (chunk*16).
    auto stage = [&](int buf, int k0) {
        #pragma unroll
        for (int c = 0; c < 2; ++c) {
            const int chw = c * 256 + wid * 64;        // wave-uniform base
            const int ch  = chw + lane;
            GLOAD_LDS16(&encb[(size_t)(m0 + (ch >> 2)) * HIDDEN + k0 + (ch & 3) * 8],
                        (char*)&As[buf][0][0] + (size_t)chw * 16);
        }
        #pragma unroll
        for (int c = 0; c < 4; ++c) {
            const int chw = c * 256 + wid * 64;
            const int ch  = chw + lane;
            GLOAD_LDS16(&Wb[(size_t)(n0 + (ch >> 2)) * HIDDEN + k0 + (ch & 3) * 8],
                        (char*)&Bs[buf][0][0] + (size_t)chw * 16);
        }
    };

    stage(0, 0);
    stage(1, BK);
    asm volatile("s_waitcnt vmcnt(6)" ::: "memory");   // buf0's 6 retired
    __builtin_amdgcn_s_barrier();

    f32x4 acc[4][8] = {};

    #pragma unroll 1
    for (int t = 0; t < NKS; ++t) {
        const int cur = t % 3;
        if (t + 2 < NKS) stage((t + 2) % 3, (t + 2) * BK);

        bf16x8 af[4], bf[8];
        #pragma unroll
        for (int fi = 0; fi < 4; ++fi)
            af[fi] = *(const bf16x8*)&As[cur][wm + fi * 16 + lr][kb];
        #pragma unroll
        for (int fj = 0; fj < 8; ++fj)
            bf[fj] = *(const bf16x8*)&Bs[cur][wn + fj * 16 + lr][kb];

        #pragma unroll
        for (int fi = 0; fi < 4; ++fi)
            #pragma unroll
            for (int fj = 0; fj < 8; ++fj)
                acc[fi][fj] = __builtin_amdgcn_mfma_f32_16x16x32_bf16(
                    af[fi], bf[fj], acc[fi][fj], 0, 0, 0);

        if (t + 1 < NKS) {
            asm volatile("s_waitcnt lgkmcnt(0)" ::: "memory"); // cur reads done
            __builtin_amdgcn_sched_barrier(0);
            if (t + 2 < NKS) asm volatile("s_waitcnt vmcnt(6)" ::: "memory");
            else             asm volatile("s_waitcnt vmcnt(0)" ::: "memory");
            __builtin_amdgcn_s_barrier();      // buf(t+1) published to all
        }
    }

    // Epilogue. C/D layout: col = lane&15, row = (lane>>4)*4 + reg.
    const int rowgrp = lane >> 4;
    const int col    = lane & 15;
    const int b      = m0 >> 11;               // batch (block-uniform)
    const float* decb = dec + (size_t)b * HIDDEN;

    float2 dv[8];
    #pragma unroll
    for (int fj = 0; fj < 8; ++fj) {
        const int n = n0 + wn + fj * 16 + col;
        dv[fj] = make_float2(decb[n], v[n]);
    }

    const size_t plane = (size_t)(nt * 2 + (wid & 1)) * MTOT;  // wave-private

    #pragma unroll
    for (int fi = 0; fi < 4; ++fi) {
        #pragma unroll
        for (int r = 0; r < 4; ++r) {
            const int m = m0 + wm + fi * 16 + rowgrp * 4 + r;
            float rp = 0.f;
            #pragma unroll
            for (int fj = 0; fj < 8; ++fj)
                rp = fmaf(fast_tanh(acc[fi][fj][r] + dv[fj].x), dv[fj].y, rp);
            rp += __shfl_xor(rp, 1, 64);
            rp += __shfl_xor(rp, 2, 64);
            rp += __shfl_xor(rp, 4, 64);
            rp += __shfl_xor(rp, 8, 64);
            if (col == 0) {
                if (PARTIALS) outp[plane + m] = rp;
                else          atomicAdd(&outp[m], rp);
            }
        }
    }
}

// ---------------------------------------------------------------------------
// softmax over SEQ per batch. PARTIALS: sum 8 partial score planes first.
// ---------------------------------------------------------------------------
template <bool PARTIALS>
__global__ __launch_bounds__(256) void softmax_k(
    const float* __restrict__ scores, float* __restrict__ wts)
{
    __shared__ float redmax[4];
    __shared__ float redsum[4];
    const int b = blockIdx.x;
    const int tid = threadIdx.x;

    float vals[8];
    float lmax = -1e30f;
    #pragma unroll
    for (int j = 0; j < 8; ++j) {
        const int idx = b * SEQ + tid + j * 256;
        float s;
        if (PARTIALS) {
            s = 0.f;
            #pragma unroll
            for (int p = 0; p < N_PLANES; ++p)
                s += scores[(size_t)p * MTOT + idx];
        } else {
            s = scores[idx];
        }
        vals[j] = s;
        lmax = fmaxf(lmax, s);
    }
    #pragma unroll
    for (int off = 1; off < 64; off <<= 1)
        lmax = fmaxf(lmax, __shfl_xor(lmax, off, 64));
    if ((tid & 63) == 0) redmax[tid >> 6] = lmax;
    __syncthreads();
    const float gmax = fmaxf(fmaxf(redmax[0], redmax[1]),
                             fmaxf(redmax[2], redmax[3]));

    float lsum = 0.f;
    #pragma unroll
    for (int j = 0; j < 8; ++j) {
        vals[j] = expf(vals[j] - gmax);
        lsum += vals[j];
    }
    #pragma unroll
    for (int off = 1; off < 64; off <<= 1)
        lsum += __shfl_xor(lsum, off, 64);
    if ((tid & 63) == 0) redsum[tid >> 6] = lsum;
    __syncthreads();
    const float inv = 1.f / (redsum[0] + redsum[1] + redsum[2] + redsum[3]);

    #pragma unroll
    for (int j = 0; j < 8; ++j)
        wts[b * SEQ + tid + j * 256] = vals[j] * inv;
}

// ---------------------------------------------------------------------------
// context[b,h] = sum_s w[b,s] * enc[b,s,h], reading the bf16 enc copy.
// ---------------------------------------------------------------------------
__global__ __launch_bounds__(256) void context_bf16_k(
    const unsigned short* __restrict__ encb,
    const float* __restrict__ w,
    float* __restrict__ ctx)
{
    const int b     = blockIdx.x >> 3;
    const int chunk = blockIdx.x & 7;
    const int sOff  = threadIdx.x >> 4;
    const int hg    = threadIdx.x & 15;
    const int h     = chunk * 128 + hg * 8;

    float acc[8] = {};
    for (int s = sOff; s < SEQ; s += 16) {
        const float ws = w[b * SEQ + s];
        ushort8 e = *(const ushort8*)&encb[(size_t)(b * SEQ + s) * HIDDEN + h];
        #pragma unroll
        for (int j = 0; j < 8; ++j)
            acc[j] = fmaf(ws, __uint_as_float((unsigned)e[j] << 16), acc[j]);
    }
    __shared__ float red[16][128];
    #pragma unroll
    for (int j = 0; j < 8; ++j) red[sOff][hg * 8 + j] = acc[j];
    __syncthreads();
    if (threadIdx.x < 128) {
        float r = 0.f;
        #pragma unroll
        for (int g = 0; g < 16; ++g) r += red[g][threadIdx.x];
        ctx[b * HIDDEN + chunk * 128 + threadIdx.x] = r;
    }
}

// ---------------------------------------------------------------------------
// Fallback fp32 path, used only if ws_size is too small for bf16 copies.
// ---------------------------------------------------------------------------
__global__ __launch_bounds__(256) void score_gemm_f32(
    const float* __restrict__ enc, const float* __restrict__ W,
    const float* __restrict__ dec, const float* __restrict__ v,
    float* __restrict__ scores)
{
    __shared__ float As[16][64 + 1];
    __shared__ float Bs[16][64 + 1];
    const int tid = threadIdx.x;
    const int m0 = (blockIdx.x >> 4) * 64;
    const int n0 = (blockIdx.x & 15) * 64;
    const int ty = tid >> 4, tx = tid & 15;
    const int lr = tid >> 2, lc = tid & 3;
    float acc[4][4] = {};
    for (int k0 = 0; k0 < HIDDEN; k0 += 16) {
        float4 a = *(const float4*)&enc[(size_t)(m0 + lr) * HIDDEN + k0 + lc * 4];
        float4 b = *(const float4*)&W  [(size_t)(n0 + lr) * HIDDEN + k0 + lc * 4];
        __syncthreads();
        As[lc*4+0][lr]=a.x; As[lc*4+1][lr]=a.y; As[lc*4+2][lr]=a.z; As[lc*4+3][lr]=a.w;
        Bs[lc*4+0][lr]=b.x; Bs[lc*4+1][lr]=b.y; Bs[lc*4+2][lr]=b.z; Bs[lc*4+3][lr]=b.w;
        __syncthreads();
        #pragma unroll
        for (int k = 0; k < 16; ++k) {
            float4 av = *(const float4*)&As[k][ty * 4];
            float4 bv = *(const float4*)&Bs[k][tx * 4];
            float aa[4] = {av.x, av.y, av.z, av.w};
            float bb[4] = {bv.x, bv.y, bv.z, bv.w};
            #pragma unroll
            for (int i = 0; i < 4; ++i)
                #pragma unroll
                for (int j = 0; j < 4; ++j)
                    acc[i][j] = fmaf(aa[i], bb[j], acc[i][j]);
        }
    }
    float rowpart[4];
    #pragma unroll
    for (int i = 0; i < 4; ++i) {
        const int m = m0 + ty * 4 + i;
        const int b = m >> 11;
        float rp = 0.f;
        #pragma unroll
        for (int j = 0; j < 4; ++j) {
            const int n = n0 + tx * 4 + j;
            rp = fmaf(fast_tanh(acc[i][j] + dec[b * HIDDEN + n]), v[n], rp);
        }
        rowpart[i] = rp;
    }
    #pragma unroll
    for (int off = 1; off <= 8; off <<= 1)
        #pragma unroll
        for (int i = 0; i < 4; ++i)
            rowpart[i] += __shfl_xor(rowpart[i], off, 64);
    if (tx == 0)
        #pragma unroll
        for (int i = 0; i < 4; ++i)
            atomicAdd(&scores[m0 + ty * 4 + i], rowpart[i]);
}

__global__ __launch_bounds__(256) void context_f32_k(
    const float* __restrict__ enc, const float* __restrict__ w,
    float* __restrict__ ctx)
{
    const int b = blockIdx.x >> 3, chunk = blockIdx.x & 7;
    const int sOff = threadIdx.x >> 6, hp = threadIdx.x & 63;
    const int h = chunk * 128 + hp * 2;
    float2 acc = {0.f, 0.f};
    for (int s = sOff; s < SEQ; s += 4) {
        const float ws = w[b * SEQ + s];
        const float2 e = *(const float2*)&enc[(size_t)(b * SEQ + s) * HIDDEN + h];
        acc.x = fmaf(ws, e.x, acc.x);
        acc.y = fmaf(ws, e.y, acc.y);
    }
    __shared__ float2 red[4][64];
    red[sOff][hp] = acc;
    __syncthreads();
    if (sOff == 0) {
        float2 r = red[0][hp];
        #pragma unroll
        for (int t = 1; t < 4; ++t) { r.x += red[t][hp].x; r.y += red[t][hp].y; }
        ctx[b * HIDDEN + h] = r.x;
        ctx[b * HIDDEN + h + 1] = r.y;
    }
}

// ---------------------------------------------------------------------------
extern "C" void kernel_launch(void* const* d_in, const int* in_sizes, int n_in,
                              void* d_out, int out_size, void* d_ws, size_t ws_size,
                              hipStream_t stream) {
    const float* dec = (const float*)d_in[0];   // [32, 1024]
    const float* enc = (const float*)d_in[1];   // [32, 2048, 1024]
    const float* W   = (const float*)d_in[2];   // [1024, 1024]
    const float* v   = (const float*)d_in[3];   // [1, 1024]

    float* out = (float*)d_out;
    float* ctx = out;                           // [32, 1024]
    float* wts = out + BATCH * HIDDEN;          // [32, 2048]

    const size_t part_bytes   = (size_t)N_PLANES * MTOT * sizeof(float); // 2 MiB
    const size_t scores_bytes = (size_t)MTOT * sizeof(float);            // 256 KiB
    const size_t encb_bytes   = (size_t)MTOT * HIDDEN * 2;               // 128 MiB
    const size_t wb_bytes     = (size_t)HIDDEN * HIDDEN * 2;             // 2 MiB

    const size_t need_part   = part_bytes + encb_bytes + wb_bytes;
    const size_t need_atomic = scores_bytes + encb_bytes + wb_bytes;

    if (ws_size >= need_part) {
        float* partial = (float*)d_ws;
        unsigned short* encb = (unsigned short*)((char*)d_ws + part_bytes);
        unsigned short* Wb   = (unsigned short*)((char*)d_ws + part_bytes + encb_bytes);

        convert_k<<<dim3(2048), dim3(256), 0, stream>>>(enc, encb, W, Wb);
        score_gemm_mfma<true><<<dim3(2048), dim3(256), 0, stream>>>(encb, Wb, dec, v, partial);
        softmax_k<true><<<dim3(BATCH), dim3(256), 0, stream>>>(partial, wts);
        context_bf16_k<<<dim3(BATCH * 8), dim3(256), 0, stream>>>(encb, wts, ctx);
    } else if (ws_size >= need_atomic) {
        float* scores = (float*)d_ws;
        unsigned short* encb = (unsigned short*)((char*)d_ws + scores_bytes);
        unsigned short* Wb   = (unsigned short*)((char*)d_ws + scores_bytes + encb_bytes);

        hipMemsetAsync(scores, 0, scores_bytes, stream);
        convert_k<<<dim3(2048), dim3(256), 0, stream>>>(enc, encb, W, Wb);
        score_gemm_mfma<false><<<dim3(2048), dim3(256), 0, stream>>>(encb, Wb, dec, v, scores);
        softmax_k<false><<<dim3(BATCH), dim3(256), 0, stream>>>(scores, wts);
        context_bf16_k<<<dim3(BATCH * 8), dim3(256), 0, stream>>>(encb, wts, ctx);
    } else {
        float* scores = (float*)d_ws;
        hipMemsetAsync(scores, 0, scores_bytes, stream);
        score_gemm_f32<<<dim3(16384), dim3(256), 0, stream>>>(enc, W, dec, v, scores);
        softmax_k<false><<<dim3(BATCH), dim3(256), 0, stream>>>(scores, wts);
        context_f32_k<<<dim3(BATCH * 8), dim3(256), 0, stream>>>(enc, wts, ctx);
    }
}

// Round 7
// 270.112 us; speedup vs baseline: 1.4171x; 1.0433x over previous
//
#include <hip/hip_runtime.h>
#include <hip/hip_bf16.h>
#include <math.h>

#define HIDDEN 1024
#define BATCH 32
#define SEQ 2048
#define MTOT (BATCH * SEQ)   // 65536 rows
#define N_PLANES 8           // 4 n-tiles x 2 wn-waves

#define BM 128
#define BN 256
#define BK 32
#define NKS (HIDDEN / BK)    // 32 K-steps

typedef __attribute__((ext_vector_type(8))) short          bf16x8;
typedef __attribute__((ext_vector_type(8))) unsigned short ushort8;
typedef __attribute__((ext_vector_type(4))) float          f32x4;

#define GLOAD_LDS16(g, l) __builtin_amdgcn_global_load_lds( \
    (const __attribute__((address_space(1))) void*)(g),      \
    (__attribute__((address_space(3))) void*)(l), 16, 0, 0)

#define BARRIER() asm volatile("s_barrier" ::: "memory")
#define WAITL0()  asm volatile("s_waitcnt lgkmcnt(0)" ::: "memory")
#define WAITV6()  asm volatile("s_waitcnt vmcnt(6)" ::: "memory")
#define WAITV0()  asm volatile("s_waitcnt vmcnt(0)" ::: "memory")
#define SCHED0()  __builtin_amdgcn_sched_barrier(0)

// tanh(x) = 1 - 2/(exp2(x*2*log2e)+1); saturates exactly via exp2 inf/0.
__device__ __forceinline__ float fast_tanh(float x) {
    float e = __builtin_amdgcn_exp2f(x * 2.8853900817779268f);
    return 1.0f - 2.0f * __builtin_amdgcn_rcpf(1.0f + e);
}

// ---------------------------------------------------------------------------
// fp32 -> bf16 (RNE) conversion for enc and W in ONE launch.
// ---------------------------------------------------------------------------
__global__ __launch_bounds__(256) void convert_k(
    const float* __restrict__ enc, unsigned short* __restrict__ encb,
    const float* __restrict__ W,   unsigned short* __restrict__ Wb)
{
    const int n8_enc = MTOT * (HIDDEN / 8);
    const int n8_tot = n8_enc + HIDDEN * (HIDDEN / 8);
    for (int i = blockIdx.x * blockDim.x + threadIdx.x; i < n8_tot;
         i += gridDim.x * blockDim.x) {
        const float* src; unsigned short* dst; size_t idx;
        if (i < n8_enc) { src = enc; dst = encb; idx = (size_t)i; }
        else            { src = W;   dst = Wb;   idx = (size_t)(i - n8_enc); }
        float4 a = ((const float4*)src)[idx * 2];
        float4 b = ((const float4*)src)[idx * 2 + 1];
        float va[8] = {a.x, a.y, a.z, a.w, b.x, b.y, b.z, b.w};
        ushort8 r;
        #pragma unroll
        for (int j = 0; j < 8; ++j) {
            unsigned u = __float_as_uint(va[j]);
            unsigned rnd = u + 0x7FFFu + ((u >> 16) & 1u);   // RNE
            r[j] = (unsigned short)(rnd >> 16);
        }
        *(ushort8*)&dst[idx * 8] = r;
    }
}

// ---------------------------------------------------------------------------
// MFMA score GEMM: BM=128 x BN=256, BK=32, 4 waves (wave tile 64x128).
// 3-buffer LDS rotation, 2-ahead prefetch, counted vmcnt(6) (round-6 ledger),
// NOW with 2-phase-per-K-step interleave (T3), LDS XOR-swizzle via
// pre-swizzled global source (T2, rule #21), and setprio (T5):
//   P0: 8 ds_read (af0-3,bf0-3) | stage A+B0 of buf t+2 | bar | lgkm0 |
//       prio1 16 MFMA prio0 | bar
//   P1: 4 ds_read (bf4-7)      | stage B1 of buf t+2    | bar | lgkm0 |
//       prio1 16 MFMA prio0 | vmcnt(6 steady/0 tail) | bar
// Swizzle: LDS 16B-slot' = slot ^ (row&3); source k-offset pre-swizzled so
// the swizzled read returns the lane's canonical kb. 8-way -> 4-way conflict.
// Race audit: every wave executes lgkmcnt(0) (P-phase) before each end-of-
// step barrier, so all ds_reads of buffer b drain before b is re-staged
// (re-stage of b happens >= 1 full barrier after its last read).
// PARTIALS=true : wave-private planes partial[(nt*2+(wid&1))*MTOT + m].
// ---------------------------------------------------------------------------
template <bool PARTIALS>
__global__ __launch_bounds__(256, 2) void score_gemm_mfma(
    const unsigned short* __restrict__ encb,  // [MTOT][HIDDEN] bf16
    const unsigned short* __restrict__ Wb,    // [HIDDEN][HIDDEN] bf16 (out,in)
    const float* __restrict__ dec,            // [BATCH][HIDDEN]
    const float* __restrict__ v,              // [HIDDEN]
    float* __restrict__ outp)                 // partial[8][MTOT] or scores[MTOT]
{
    __shared__ unsigned short As[3][BM][BK];   // 24 KiB
    __shared__ unsigned short Bs[3][BN][BK];   // 48 KiB

    // XCD-grouping swizzle (bijective: 2048 blocks = 8 xcds x 256 slots):
    const int bid  = blockIdx.x;
    const int xcd  = bid & 7;
    const int slot = bid >> 3;                 // 0..255
    const int mt   = xcd * 64 + (slot >> 2);   // 0..511
    const int nt   = slot & 3;                 // 0..3
    const int m0   = mt * BM;
    const int n0   = nt * BN;

    const int tid  = threadIdx.x;
    const int wid  = tid >> 6;
    const int lane = tid & 63;
    const int wm   = (wid >> 1) * 64;          // 0 / 64
    const int wn   = (wid & 1) * 128;          // 0 / 128

    // swizzled read: byte slot = ((lane>>4) ^ (lane&3)) * 16 within 64B row
    const int rowb = (lane & 15) * 64;
    const int swzb = (((lane >> 4) ^ (lane & 3)) * 16);

    // stage helpers: LDS dest linear (chunk*16), global k pre-swizzled
    auto stageA = [&](int buf, int k0) {
        #pragma unroll
        for (int c = 0; c < 2; ++c) {
            const int chw = c * 256 + wid * 64;
            const int ch  = chw + lane;
            const int row = ch >> 2;
            const int gk  = k0 + (((ch & 3) ^ (row & 3)) * 8);
            GLOAD_LDS16(&encb[(size_t)(m0 + row) * HIDDEN + gk],
                        (char*)&As[buf][0][0] + (size_t)chw * 16);
        }
    };
    auto stageB = [&](int buf, int k0, int half) {
        #pragma unroll
        for (int c = 0; c < 2; ++c) {
            const int chw = (half * 2 + c) * 256 + wid * 64;
            const int ch  = chw + lane;
            const int row = ch >> 2;
            const int gk  = k0 + (((ch & 3) ^ (row & 3)) * 8);
            GLOAD_LDS16(&Wb[(size_t)(n0 + row) * HIDDEN + gk],
                        (char*)&Bs[buf][0][0] + (size_t)chw * 16);
        }
    };

    // prologue: 2-deep prefetch; vmcnt(6) leaves buf1's 6 in flight
    stageA(0, 0);      stageB(0, 0, 0);  stageB(0, 0, 1);
    stageA(1, BK);     stageB(1, BK, 0); stageB(1, BK, 1);
    WAITV6(); SCHED0();
    BARRIER();

    f32x4 acc[4][8] = {};

    #pragma unroll 1
    for (int t = 0; t < NKS; ++t) {
        const int cur  = t % 3;
        const int nxt  = (t + 2) % 3;
        const bool more = (t + 2 < NKS);
        const int knxt = (t + 2) * BK;
        const char* Ab = (const char*)&As[cur][0][0];
        const char* Bb = (const char*)&Bs[cur][0][0];

        bf16x8 af[4], bf[8];

        // ---------------- phase 0 ----------------
        #pragma unroll
        for (int fi = 0; fi < 4; ++fi)
            af[fi] = *(const bf16x8*)(Ab + (wm + fi * 16) * 64 + rowb + swzb);
        #pragma unroll
        for (int fj = 0; fj < 4; ++fj)
            bf[fj] = *(const bf16x8*)(Bb + (wn + fj * 16) * 64 + rowb + swzb);
        if (more) { stageA(nxt, knxt); stageB(nxt, knxt, 0); }
        BARRIER(); WAITL0(); SCHED0();
        __builtin_amdgcn_s_setprio(1);
        #pragma unroll
        for (int fi = 0; fi < 4; ++fi)
            #pragma unroll
            for (int fj = 0; fj < 4; ++fj)
                acc[fi][fj] = __builtin_amdgcn_mfma_f32_16x16x32_bf16(
                    af[fi], bf[fj], acc[fi][fj], 0, 0, 0);
        __builtin_amdgcn_s_setprio(0);
        SCHED0();
        BARRIER();

        // ---------------- phase 1 ----------------
        #pragma unroll
        for (int fj = 4; fj < 8; ++fj)
            bf[fj] = *(const bf16x8*)(Bb + (wn + fj * 16) * 64 + rowb + swzb);
        if (more) stageB(nxt, knxt, 1);
        BARRIER(); WAITL0(); SCHED0();
        __builtin_amdgcn_s_setprio(1);
        #pragma unroll
        for (int fi = 0; fi < 4; ++fi)
            #pragma unroll
            for (int fj = 4; fj < 8; ++fj)
                acc[fi][fj] = __builtin_amdgcn_mfma_f32_16x16x32_bf16(
                    af[fi], bf[fj], acc[fi][fj], 0, 0, 0);
        __builtin_amdgcn_s_setprio(0);
        SCHED0();
        if (more)              { WAITV6(); }
        else if (t + 1 < NKS)  { WAITV0(); }
        SCHED0();
        if (t + 1 < NKS) BARRIER();
    }

    // Epilogue. C/D layout: col = lane&15, row = (lane>>4)*4 + reg.
    const int rowgrp = lane >> 4;
    const int col    = lane & 15;
    const int b      = m0 >> 11;               // batch (block-uniform)
    const float* decb = dec + (size_t)b * HIDDEN;

    float2 dv[8];
    #pragma unroll
    for (int fj = 0; fj < 8; ++fj) {
        const int n = n0 + wn + fj * 16 + col;
        dv[fj] = make_float2(decb[n], v[n]);
    }

    const size_t plane = (size_t)(nt * 2 + (wid & 1)) * MTOT;  // wave-private

    #pragma unroll
    for (int fi = 0; fi < 4; ++fi) {
        #pragma unroll
        for (int r = 0; r < 4; ++r) {
            const int m = m0 + wm + fi * 16 + rowgrp * 4 + r;
            float rp = 0.f;
            #pragma unroll
            for (int fj = 0; fj < 8; ++fj)
                rp = fmaf(fast_tanh(acc[fi][fj][r] + dv[fj].x), dv[fj].y, rp);
            rp += __shfl_xor(rp, 1, 64);
            rp += __shfl_xor(rp, 2, 64);
            rp += __shfl_xor(rp, 4, 64);
            rp += __shfl_xor(rp, 8, 64);
            if (col == 0) {
                if (PARTIALS) outp[plane + m] = rp;
                else          atomicAdd(&outp[m], rp);
            }
        }
    }
}

// ---------------------------------------------------------------------------
// softmax over SEQ per batch. PARTIALS: sum 8 partial score planes first.
// ---------------------------------------------------------------------------
template <bool PARTIALS>
__global__ __launch_bounds__(256) void softmax_k(
    const float* __restrict__ scores, float* __restrict__ wts)
{
    __shared__ float redmax[4];
    __shared__ float redsum[4];
    const int b = blockIdx.x;
    const int tid = threadIdx.x;

    float vals[8];
    float lmax = -1e30f;
    #pragma unroll
    for (int j = 0; j < 8; ++j) {
        const int idx = b * SEQ + tid + j * 256;
        float s;
        if (PARTIALS) {
            s = 0.f;
            #pragma unroll
            for (int p = 0; p < N_PLANES; ++p)
                s += scores[(size_t)p * MTOT + idx];
        } else {
            s = scores[idx];
        }
        vals[j] = s;
        lmax = fmaxf(lmax, s);
    }
    #pragma unroll
    for (int off = 1; off < 64; off <<= 1)
        lmax = fmaxf(lmax, __shfl_xor(lmax, off, 64));
    if ((tid & 63) == 0) redmax[tid >> 6] = lmax;
    __syncthreads();
    const float gmax = fmaxf(fmaxf(redmax[0], redmax[1]),
                             fmaxf(redmax[2], redmax[3]));

    float lsum = 0.f;
    #pragma unroll
    for (int j = 0; j < 8; ++j) {
        vals[j] = expf(vals[j] - gmax);
        lsum += vals[j];
    }
    #pragma unroll
    for (int off = 1; off < 64; off <<= 1)
        lsum += __shfl_xor(lsum, off, 64);
    if ((tid & 63) == 0) redsum[tid >> 6] = lsum;
    __syncthreads();
    const float inv = 1.f / (redsum[0] + redsum[1] + redsum[2] + redsum[3]);

    #pragma unroll
    for (int j = 0; j < 8; ++j)
        wts[b * SEQ + tid + j * 256] = vals[j] * inv;
}

// ---------------------------------------------------------------------------
// context[b,h] = sum_s w[b,s] * enc[b,s,h], reading the bf16 enc copy.
// ---------------------------------------------------------------------------
__global__ __launch_bounds__(256) void context_bf16_k(
    const unsigned short* __restrict__ encb,
    const float* __restrict__ w,
    float* __restrict__ ctx)
{
    const int b     = blockIdx.x >> 3;
    const int chunk = blockIdx.x & 7;
    const int sOff  = threadIdx.x >> 4;
    const int hg    = threadIdx.x & 15;
    const int h     = chunk * 128 + hg * 8;

    float acc[8] = {};
    for (int s = sOff; s < SEQ; s += 16) {
        const float ws = w[b * SEQ + s];
        ushort8 e = *(const ushort8*)&encb[(size_t)(b * SEQ + s) * HIDDEN + h];
        #pragma unroll
        for (int j = 0; j < 8; ++j)
            acc[j] = fmaf(ws, __uint_as_float((unsigned)e[j] << 16), acc[j]);
    }
    __shared__ float red[16][128];
    #pragma unroll
    for (int j = 0; j < 8; ++j) red[sOff][hg * 8 + j] = acc[j];
    __syncthreads();
    if (threadIdx.x < 128) {
        float r = 0.f;
        #pragma unroll
        for (int g = 0; g < 16; ++g) r += red[g][threadIdx.x];
        ctx[b * HIDDEN + chunk * 128 + threadIdx.x] = r;
    }
}

// ---------------------------------------------------------------------------
// Fallback fp32 path, used only if ws_size is too small for bf16 copies.
// ---------------------------------------------------------------------------
__global__ __launch_bounds__(256) void score_gemm_f32(
    const float* __restrict__ enc, const float* __restrict__ W,
    const float* __restrict__ dec, const float* __restrict__ v,
    float* __restrict__ scores)
{
    __shared__ float As[16][64 + 1];
    __shared__ float Bs[16][64 + 1];
    const int tid = threadIdx.x;
    const int m0 = (blockIdx.x >> 4) * 64;
    const int n0 = (blockIdx.x & 15) * 64;
    const int ty = tid >> 4, tx = tid & 15;
    const int lr = tid >> 2, lc = tid & 3;
    float acc[4][4] = {};
    for (int k0 = 0; k0 < HIDDEN; k0 += 16) {
        float4 a = *(const float4*)&enc[(size_t)(m0 + lr) * HIDDEN + k0 + lc * 4];
        float4 b = *(const float4*)&W  [(size_t)(n0 + lr) * HIDDEN + k0 + lc * 4];
        __syncthreads();
        As[lc*4+0][lr]=a.x; As[lc*4+1][lr]=a.y; As[lc*4+2][lr]=a.z; As[lc*4+3][lr]=a.w;
        Bs[lc*4+0][lr]=b.x; Bs[lc*4+1][lr]=b.y; Bs[lc*4+2][lr]=b.z; Bs[lc*4+3][lr]=b.w;
        __syncthreads();
        #pragma unroll
        for (int k = 0; k < 16; ++k) {
            float4 av = *(const float4*)&As[k][ty * 4];
            float4 bv = *(const float4*)&Bs[k][tx * 4];
            float aa[4] = {av.x, av.y, av.z, av.w};
            float bb[4] = {bv.x, bv.y, bv.z, bv.w};
            #pragma unroll
            for (int i = 0; i < 4; ++i)
                #pragma unroll
                for (int j = 0; j < 4; ++j)
                    acc[i][j] = fmaf(aa[i], bb[j], acc[i][j]);
        }
    }
    float rowpart[4];
    #pragma unroll
    for (int i = 0; i < 4; ++i) {
        const int m = m0 + ty * 4 + i;
        const int b = m >> 11;
        float rp = 0.f;
        #pragma unroll
        for (int j = 0; j < 4; ++j) {
            const int n = n0 + tx * 4 + j;
            rp = fmaf(fast_tanh(acc[i][j] + dec[b * HIDDEN + n]), v[n], rp);
        }
        rowpart[i] = rp;
    }
    #pragma unroll
    for (int off = 1; off <= 8; off <<= 1)
        #pragma unroll
        for (int i = 0; i < 4; ++i)
            rowpart[i] += __shfl_xor(rowpart[i], off, 64);
    if (tx == 0)
        #pragma unroll
        for (int i = 0; i < 4; ++i)
            atomicAdd(&scores[m0 + ty * 4 + i], rowpart[i]);
}

__global__ __launch_bounds__(256) void context_f32_k(
    const float* __restrict__ enc, const float* __restrict__ w,
    float* __restrict__ ctx)
{
    const int b = blockIdx.x >> 3, chunk = blockIdx.x & 7;
    const int sOff = threadIdx.x >> 6, hp = threadIdx.x & 63;
    const int h = chunk * 128 + hp * 2;
    float2 acc = {0.f, 0.f};
    for (int s = sOff; s < SEQ; s += 4) {
        const float ws = w[b * SEQ + s];
        const float2 e = *(const float2*)&enc[(size_t)(b * SEQ + s) * HIDDEN + h];
        acc.x = fmaf(ws, e.x, acc.x);
        acc.y = fmaf(ws, e.y, acc.y);
    }
    __shared__ float2 red[4][64];
    red[sOff][hp] = acc;
    __syncthreads();
    if (sOff == 0) {
        float2 r = red[0][hp];
        #pragma unroll
        for (int t = 1; t < 4; ++t) { r.x += red[t][hp].x; r.y += red[t][hp].y; }
        ctx[b * HIDDEN + h] = r.x;
        ctx[b * HIDDEN + h + 1] = r.y;
    }
}

// ---------------------------------------------------------------------------
extern "C" void kernel_launch(void* const* d_in, const int* in_sizes, int n_in,
                              void* d_out, int out_size, void* d_ws, size_t ws_size,
                              hipStream_t stream) {
    const float* dec = (const float*)d_in[0];   // [32, 1024]
    const float* enc = (const float*)d_in[1];   // [32, 2048, 1024]
    const float* W   = (const float*)d_in[2];   // [1024, 1024]
    const float* v   = (const float*)d_in[3];   // [1, 1024]

    float* out = (float*)d_out;
    float* ctx = out;                           // [32, 1024]
    float* wts = out + BATCH * HIDDEN;          // [32, 2048]

    const size_t part_bytes   = (size_t)N_PLANES * MTOT * sizeof(float); // 2 MiB
    const size_t scores_bytes = (size_t)MTOT * sizeof(float);            // 256 KiB
    const size_t encb_bytes   = (size_t)MTOT * HIDDEN * 2;               // 128 MiB
    const size_t wb_bytes     = (size_t)HIDDEN * HIDDEN * 2;             // 2 MiB

    const size_t need_part   = part_bytes + encb_bytes + wb_bytes;
    const size_t need_atomic = scores_bytes + encb_bytes + wb_bytes;

    if (ws_size >= need_part) {
        float* partial = (float*)d_ws;
        unsigned short* encb = (unsigned short*)((char*)d_ws + part_bytes);
        unsigned short* Wb   = (unsigned short*)((char*)d_ws + part_bytes + encb_bytes);

        convert_k<<<dim3(2048), dim3(256), 0, stream>>>(enc, encb, W, Wb);
        score_gemm_mfma<true><<<dim3(2048), dim3(256), 0, stream>>>(encb, Wb, dec, v, partial);
        softmax_k<true><<<dim3(BATCH), dim3(256), 0, stream>>>(partial, wts);
        context_bf16_k<<<dim3(BATCH * 8), dim3(256), 0, stream>>>(encb, wts, ctx);
    } else if (ws_size >= need_atomic) {
        float* scores = (float*)d_ws;
        unsigned short* encb = (unsigned short*)((char*)d_ws + scores_bytes);
        unsigned short* Wb   = (unsigned short*)((char*)d_ws + scores_bytes + encb_bytes);

        hipMemsetAsync(scores, 0, scores_bytes, stream);
        convert_k<<<dim3(2048), dim3(256), 0, stream>>>(enc, encb, W, Wb);
        score_gemm_mfma<false><<<dim3(2048), dim3(256), 0, stream>>>(encb, Wb, dec, v, scores);
        softmax_k<false><<<dim3(BATCH), dim3(256), 0, stream>>>(scores, wts);
        context_bf16_k<<<dim3(BATCH * 8), dim3(256), 0, stream>>>(encb, wts, ctx);
    } else {
        float* scores = (float*)d_ws;
        hipMemsetAsync(scores, 0, scores_bytes, stream);
        score_gemm_f32<<<dim3(16384), dim3(256), 0, stream>>>(enc, W, dec, v, scores);
        softmax_k<false><<<dim3(BATCH), dim3(256), 0, stream>>>(scores, wts);
        context_f32_k<<<dim3(BATCH * 8), dim3(256), 0, stream>>>(enc, wts, ctx);
    }
}

// Round 8
// 221.849 us; speedup vs baseline: 1.7253x; 1.2175x over previous
//
#include <hip/hip_runtime.h>
#include <hip/hip_bf16.h>
#include <math.h>

#define HIDDEN 1024
#define BATCH 32
#define SEQ 2048
#define MTOT (BATCH * SEQ)   // 65536 rows
#define N_PLANES 8           // 4 n-tiles x 2 wn-waves

#define BM 128
#define BN 256
#define BK 32
#define NKS (HIDDEN / BK)    // 32 K-steps

typedef __attribute__((ext_vector_type(8))) short          bf16x8;
typedef __attribute__((ext_vector_type(8))) unsigned short ushort8;
typedef __attribute__((ext_vector_type(4))) float          f32x4;

#define GLOAD_LDS16(g, l) __builtin_amdgcn_global_load_lds( \
    (const __attribute__((address_space(1))) void*)(g),      \
    (__attribute__((address_space(3))) void*)(l), 16, 0, 0)

#define BARRIER() asm volatile("s_barrier" ::: "memory")
#define WAITL0()  asm volatile("s_waitcnt lgkmcnt(0)" ::: "memory")
#define WAITV2()  asm volatile("s_waitcnt vmcnt(2)" ::: "memory")
#define WAITV4()  asm volatile("s_waitcnt vmcnt(4)" ::: "memory")
#define WAITV0()  asm volatile("s_waitcnt vmcnt(0)" ::: "memory")
#define SCHED0()  __builtin_amdgcn_sched_barrier(0)

// tanh(x) = 1 - 2/(exp2(x*2*log2e)+1); saturates exactly via exp2 inf/0.
__device__ __forceinline__ float fast_tanh(float x) {
    float e = __builtin_amdgcn_exp2f(x * 2.8853900817779268f);
    return 1.0f - 2.0f * __builtin_amdgcn_rcpf(1.0f + e);
}

// 8x fp32 -> bf16 RNE (bit-trick, same numerics as previous rounds' convert)
__device__ __forceinline__ ushort8 cvt8(float4 lo, float4 hi) {
    float va[8] = {lo.x, lo.y, lo.z, lo.w, hi.x, hi.y, hi.z, hi.w};
    ushort8 r;
    #pragma unroll
    for (int j = 0; j < 8; ++j) {
        unsigned u = __float_as_uint(va[j]);
        r[j] = (unsigned short)((u + 0x7FFFu + ((u >> 16) & 1u)) >> 16);
    }
    return r;
}

// ---------------------------------------------------------------------------
// fp32 -> bf16 (RNE) conversion for W ONLY (4 MB; enc conversion is fused
// into the GEMM's A-staging now). 512 blocks x 256 thr x 1 chunk.
// ---------------------------------------------------------------------------
__global__ __launch_bounds__(256) void convert_w_k(
    const float* __restrict__ W, unsigned short* __restrict__ Wb)
{
    const int i = blockIdx.x * blockDim.x + threadIdx.x;   // 131072 chunks
    float4 a = ((const float4*)W)[(size_t)i * 2];
    float4 b = ((const float4*)W)[(size_t)i * 2 + 1];
    *(ushort8*)&Wb[(size_t)i * 8] = cvt8(a, b);
}

// ---------------------------------------------------------------------------
// MFMA score GEMM, BM=128 x BN=256, BK=32, 4 waves, 3-buffer rotation,
// 2-phase interleave + setprio (round-7 structure), with FUSED A-CONVERSION:
// A is read as fp32 from enc, issued early (P0), cvt+ds_write late (P1) —
// T14 async-split; LDS stays bf16 so the LDS/MFMA balance is unchanged.
// vmcnt ledger per step t (issue order: A(4), Bh0(2) in P0; Bh1(2) in P1):
//   P1 WAITV2: forces A(t+2) done (cvt input) and B(t+1) done (early, due
//              end-of-step anyway). end-of-step WAITV4: leaves B(t+2) flying.
// Race audit: As[nxt] ds_writes drain at writer's P1 WAITL0 (pre-MFMA),
// readers touch buf t+2 two barriers later. As buf reads happen only in P0,
// Bs-half1 reads only in P1; re-stage of a buffer is always >= 1 barrier
// after its last reader's own lgkm drain.
// PARTIALS=true : wave-private planes partial[(nt*2+(wid&1))*MTOT + m].
// ---------------------------------------------------------------------------
template <bool PARTIALS>
__global__ __launch_bounds__(256, 2) void score_gemm_mfma(
    const float* __restrict__ enc,            // [MTOT][HIDDEN] fp32
    const unsigned short* __restrict__ Wb,    // [HIDDEN][HIDDEN] bf16 (out,in)
    const float* __restrict__ dec,            // [BATCH][HIDDEN]
    const float* __restrict__ v,              // [HIDDEN]
    float* __restrict__ outp)                 // partial[8][MTOT] or scores[MTOT]
{
    __shared__ unsigned short As[3][BM][BK];   // 24 KiB
    __shared__ unsigned short Bs[3][BN][BK];   // 48 KiB

    // XCD-grouping swizzle (bijective: 2048 blocks = 8 xcds x 256 slots)
    const int bid  = blockIdx.x;
    const int xcd  = bid & 7;
    const int slot = bid >> 3;                 // 0..255
    const int mt   = xcd * 64 + (slot >> 2);   // 0..511
    const int nt   = slot & 3;                 // 0..3
    const int m0   = mt * BM;
    const int n0   = nt * BN;

    const int tid  = threadIdx.x;
    const int wid  = tid >> 6;
    const int lane = tid & 63;
    const int wm   = (wid >> 1) * 64;          // 0 / 64
    const int wn   = (wid & 1) * 128;          // 0 / 128

    // swizzled LDS read: byte slot = ((lane>>4) ^ (lane&3)) * 16 in 64B row
    const int rowb = (lane & 15) * 64;
    const int swzb = (((lane >> 4) ^ (lane & 3)) * 16);

    // A chunks (2 per thread); global k pre-swizzled to keep LDS linear
    const int chA0  = wid * 64 + lane;
    const int chA1  = 256 + wid * 64 + lane;
    const int rowA0 = chA0 >> 2, rowA1 = chA1 >> 2;
    const float* encA0 = &enc[(size_t)(m0 + rowA0) * HIDDEN
                              + (((chA0 & 3) ^ (rowA0 & 3)) * 8)];
    const float* encA1 = &enc[(size_t)(m0 + rowA1) * HIDDEN
                              + (((chA1 & 3) ^ (rowA1 & 3)) * 8)];

    auto loadA = [&](int k0, float4& l0, float4& h0, float4& l1, float4& h1) {
        l0 = *(const float4*)(encA0 + k0);
        h0 = *(const float4*)(encA0 + k0 + 4);
        l1 = *(const float4*)(encA1 + k0);
        h1 = *(const float4*)(encA1 + k0 + 4);
    };
    auto writeA = [&](int buf, float4 l0, float4 h0, float4 l1, float4 h1) {
        *(ushort8*)((char*)&As[buf][0][0] + (size_t)chA0 * 16) = cvt8(l0, h0);
        *(ushort8*)((char*)&As[buf][0][0] + (size_t)chA1 * 16) = cvt8(l1, h1);
    };
    auto stageB = [&](int buf, int k0, int half) {
        #pragma unroll
        for (int c = 0; c < 2; ++c) {
            const int chw = (half * 2 + c) * 256 + wid * 64;
            const int ch  = chw + lane;
            const int row = ch >> 2;
            const int gk  = k0 + (((ch & 3) ^ (row & 3)) * 8);
            GLOAD_LDS16(&Wb[(size_t)(n0 + row) * HIDDEN + gk],
                        (char*)&Bs[buf][0][0] + (size_t)chw * 16);
        }
    };

    // prologue: 2-deep prefetch. Order: A0(4), B0(4), A1(4), B1(4).
    {
        float4 p0l0, p0h0, p0l1, p0h1, p1l0, p1h0, p1l1, p1h1;
        loadA(0, p0l0, p0h0, p0l1, p0h1);
        stageB(0, 0, 0);  stageB(0, 0, 1);
        loadA(BK, p1l0, p1h0, p1l1, p1h1);
        stageB(1, BK, 0); stageB(1, BK, 1);
        asm volatile("s_waitcnt vmcnt(12)" ::: "memory"); SCHED0(); // A0 done
        writeA(0, p0l0, p0h0, p0l1, p0h1);
        WAITV4(); SCHED0();                                        // A1+B0 done
        writeA(1, p1l0, p1h0, p1l1, p1h1);
        WAITL0(); SCHED0();
        BARRIER();
    }

    f32x4 acc[4][8] = {};

    #pragma unroll 1
    for (int t = 0; t < NKS; ++t) {
        const int cur  = t % 3;
        const int nxt  = (t + 2) % 3;
        const bool more = (t + 2 < NKS);
        const int knxt = (t + 2) * BK;
        const char* Ab = (const char*)&As[cur][0][0];
        const char* Bb = (const char*)&Bs[cur][0][0];

        bf16x8 af[4], bf[8];
        float4 al0, ah0, al1, ah1;

        // ---------------- phase 0 ----------------
        #pragma unroll
        for (int fi = 0; fi < 4; ++fi)
            af[fi] = *(const bf16x8*)(Ab + (wm + fi * 16) * 64 + rowb + swzb);
        #pragma unroll
        for (int fj = 0; fj < 4; ++fj)
            bf[fj] = *(const bf16x8*)(Bb + (wn + fj * 16) * 64 + rowb + swzb);
        if (more) { loadA(knxt, al0, ah0, al1, ah1); stageB(nxt, knxt, 0); }
        BARRIER(); WAITL0(); SCHED0();
        __builtin_amdgcn_s_setprio(1);
        #pragma unroll
        for (int fi = 0; fi < 4; ++fi)
            #pragma unroll
            for (int fj = 0; fj < 4; ++fj)
                acc[fi][fj] = __builtin_amdgcn_mfma_f32_16x16x32_bf16(
                    af[fi], bf[fj], acc[fi][fj], 0, 0, 0);
        __builtin_amdgcn_s_setprio(0);
        SCHED0();
        BARRIER();

        // ---------------- phase 1 ----------------
        #pragma unroll
        for (int fj = 4; fj < 8; ++fj)
            bf[fj] = *(const bf16x8*)(Bb + (wn + fj * 16) * 64 + rowb + swzb);
        if (more) {
            WAITV2(); SCHED0();               // A(t+2) regs ready; B(t+1) done
            writeA(nxt, al0, ah0, al1, ah1);
            stageB(nxt, knxt, 1);
        }
        BARRIER(); WAITL0(); SCHED0();
        __builtin_amdgcn_s_setprio(1);
        #pragma unroll
        for (int fi = 0; fi < 4; ++fi)
            #pragma unroll
            for (int fj = 4; fj < 8; ++fj)
                acc[fi][fj] = __builtin_amdgcn_mfma_f32_16x16x32_bf16(
                    af[fi], bf[fj], acc[fi][fj], 0, 0, 0);
        __builtin_amdgcn_s_setprio(0);
        SCHED0();
        if (more)             { WAITV4(); }   // leave B(t+2) in flight
        else if (t + 1 < NKS) { WAITV0(); }
        SCHED0();
        if (t + 1 < NKS) BARRIER();
    }

    // Epilogue. C/D layout: col = lane&15, row = (lane>>4)*4 + reg.
    const int rowgrp = lane >> 4;
    const int col    = lane & 15;
    const int b      = m0 >> 11;               // batch (block-uniform)
    const float* decb = dec + (size_t)b * HIDDEN;

    float2 dv[8];
    #pragma unroll
    for (int fj = 0; fj < 8; ++fj) {
        const int n = n0 + wn + fj * 16 + col;
        dv[fj] = make_float2(decb[n], v[n]);
    }

    const size_t plane = (size_t)(nt * 2 + (wid & 1)) * MTOT;  // wave-private

    #pragma unroll
    for (int fi = 0; fi < 4; ++fi) {
        #pragma unroll
        for (int r = 0; r < 4; ++r) {
            const int m = m0 + wm + fi * 16 + rowgrp * 4 + r;
            float rp = 0.f;
            #pragma unroll
            for (int fj = 0; fj < 8; ++fj)
                rp = fmaf(fast_tanh(acc[fi][fj][r] + dv[fj].x), dv[fj].y, rp);
            rp += __shfl_xor(rp, 1, 64);
            rp += __shfl_xor(rp, 2, 64);
            rp += __shfl_xor(rp, 4, 64);
            rp += __shfl_xor(rp, 8, 64);
            if (col == 0) {
                if (PARTIALS) outp[plane + m] = rp;
                else          atomicAdd(&outp[m], rp);
            }
        }
    }
}

// ---------------------------------------------------------------------------
// softmax over SEQ per batch. PARTIALS: sum 8 partial score planes first.
// ---------------------------------------------------------------------------
template <bool PARTIALS>
__global__ __launch_bounds__(256) void softmax_k(
    const float* __restrict__ scores, float* __restrict__ wts)
{
    __shared__ float redmax[4];
    __shared__ float redsum[4];
    const int b = blockIdx.x;
    const int tid = threadIdx.x;

    float vals[8];
    float lmax = -1e30f;
    #pragma unroll
    for (int j = 0; j < 8; ++j) {
        const int idx = b * SEQ + tid + j * 256;
        float s;
        if (PARTIALS) {
            s = 0.f;
            #pragma unroll
            for (int p = 0; p < N_PLANES; ++p)
                s += scores[(size_t)p * MTOT + idx];
        } else {
            s = scores[idx];
        }
        vals[j] = s;
        lmax = fmaxf(lmax, s);
    }
    #pragma unroll
    for (int off = 1; off < 64; off <<= 1)
        lmax = fmaxf(lmax, __shfl_xor(lmax, off, 64));
    if ((tid & 63) == 0) redmax[tid >> 6] = lmax;
    __syncthreads();
    const float gmax = fmaxf(fmaxf(redmax[0], redmax[1]),
                             fmaxf(redmax[2], redmax[3]));

    float lsum = 0.f;
    #pragma unroll
    for (int j = 0; j < 8; ++j) {
        vals[j] = expf(vals[j] - gmax);
        lsum += vals[j];
    }
    #pragma unroll
    for (int off = 1; off < 64; off <<= 1)
        lsum += __shfl_xor(lsum, off, 64);
    if ((tid & 63) == 0) redsum[tid >> 6] = lsum;
    __syncthreads();
    const float inv = 1.f / (redsum[0] + redsum[1] + redsum[2] + redsum[3]);

    #pragma unroll
    for (int j = 0; j < 8; ++j)
        wts[b * SEQ + tid + j * 256] = vals[j] * inv;
}

// ---------------------------------------------------------------------------
// context[b,h] = sum_s w[b,s] * enc[b,s,h], fp32 enc, float4 loads.
// Grid = 32 b x 8 h-chunks(128); thread = sOff(0..7) x quad(0..31).
// ---------------------------------------------------------------------------
__global__ __launch_bounds__(256) void context_f32_k(
    const float* __restrict__ enc,
    const float* __restrict__ w,
    float* __restrict__ ctx)
{
    const int b     = blockIdx.x >> 3;
    const int chunk = blockIdx.x & 7;
    const int sOff  = threadIdx.x >> 5;        // 0..7
    const int quad  = threadIdx.x & 31;        // 0..31
    const int h     = chunk * 128 + quad * 4;

    float4 acc = {0.f, 0.f, 0.f, 0.f};
    #pragma unroll 4
    for (int s = sOff; s < SEQ; s += 8) {
        const float ws = w[b * SEQ + s];
        const float4 e = *(const float4*)&enc[(size_t)(b * SEQ + s) * HIDDEN + h];
        acc.x = fmaf(ws, e.x, acc.x);
        acc.y = fmaf(ws, e.y, acc.y);
        acc.z = fmaf(ws, e.z, acc.z);
        acc.w = fmaf(ws, e.w, acc.w);
    }

    __shared__ float4 red[8][32];
    red[sOff][quad] = acc;
    __syncthreads();
    if (sOff == 0) {
        float4 r = red[0][quad];
        #pragma unroll
        for (int t = 1; t < 8; ++t) {
            r.x += red[t][quad].x; r.y += red[t][quad].y;
            r.z += red[t][quad].z; r.w += red[t][quad].w;
        }
        *(float4*)&ctx[b * HIDDEN + h] = r;
    }
}

// ---------------------------------------------------------------------------
// Fallback fp32 path (no workspace beyond scores).
// ---------------------------------------------------------------------------
__global__ __launch_bounds__(256) void score_gemm_f32(
    const float* __restrict__ enc, const float* __restrict__ W,
    const float* __restrict__ dec, const float* __restrict__ v,
    float* __restrict__ scores)
{
    __shared__ float As[16][64 + 1];
    __shared__ float Bs[16][64 + 1];
    const int tid = threadIdx.x;
    const int m0 = (blockIdx.x >> 4) * 64;
    const int n0 = (blockIdx.x & 15) * 64;
    const int ty = tid >> 4, tx = tid & 15;
    const int lr = tid >> 2, lc = tid & 3;
    float acc[4][4] = {};
    for (int k0 = 0; k0 < HIDDEN; k0 += 16) {
        float4 a = *(const float4*)&enc[(size_t)(m0 + lr) * HIDDEN + k0 + lc * 4];
        float4 b = *(const float4*)&W  [(size_t)(n0 + lr) * HIDDEN + k0 + lc * 4];
        __syncthreads();
        As[lc*4+0][lr]=a.x; As[lc*4+1][lr]=a.y; As[lc*4+2][lr]=a.z; As[lc*4+3][lr]=a.w;
        Bs[lc*4+0][lr]=b.x; Bs[lc*4+1][lr]=b.y; Bs[lc*4+2][lr]=b.z; Bs[lc*4+3][lr]=b.w;
        __syncthreads();
        #pragma unroll
        for (int k = 0; k < 16; ++k) {
            float4 av = *(const float4*)&As[k][ty * 4];
            float4 bv = *(const float4*)&Bs[k][tx * 4];
            float aa[4] = {av.x, av.y, av.z, av.w};
            float bb[4] = {bv.x, bv.y, bv.z, bv.w};
            #pragma unroll
            for (int i = 0; i < 4; ++i)
                #pragma unroll
                for (int j = 0; j < 4; ++j)
                    acc[i][j] = fmaf(aa[i], bb[j], acc[i][j]);
        }
    }
    float rowpart[4];
    #pragma unroll
    for (int i = 0; i < 4; ++i) {
        const int m = m0 + ty * 4 + i;
        const int b = m >> 11;
        float rp = 0.f;
        #pragma unroll
        for (int j = 0; j < 4; ++j) {
            const int n = n0 + tx * 4 + j;
            rp = fmaf(fast_tanh(acc[i][j] + dec[b * HIDDEN + n]), v[n], rp);
        }
        rowpart[i] = rp;
    }
    #pragma unroll
    for (int off = 1; off <= 8; off <<= 1)
        #pragma unroll
        for (int i = 0; i < 4; ++i)
            rowpart[i] += __shfl_xor(rowpart[i], off, 64);
    if (tx == 0)
        #pragma unroll
        for (int i = 0; i < 4; ++i)
            atomicAdd(&scores[m0 + ty * 4 + i], rowpart[i]);
}

// ---------------------------------------------------------------------------
extern "C" void kernel_launch(void* const* d_in, const int* in_sizes, int n_in,
                              void* d_out, int out_size, void* d_ws, size_t ws_size,
                              hipStream_t stream) {
    const float* dec = (const float*)d_in[0];   // [32, 1024]
    const float* enc = (const float*)d_in[1];   // [32, 2048, 1024]
    const float* W   = (const float*)d_in[2];   // [1024, 1024]
    const float* v   = (const float*)d_in[3];   // [1, 1024]

    float* out = (float*)d_out;
    float* ctx = out;                           // [32, 1024]
    float* wts = out + BATCH * HIDDEN;          // [32, 2048]

    const size_t part_bytes   = (size_t)N_PLANES * MTOT * sizeof(float); // 2 MiB
    const size_t wb_bytes     = (size_t)HIDDEN * HIDDEN * 2;             // 2 MiB
    const size_t scores_bytes = (size_t)MTOT * sizeof(float);            // 256 KiB
    const size_t need = part_bytes + wb_bytes;                           // 4 MiB

    if (ws_size >= need) {
        float* partial       = (float*)d_ws;
        unsigned short* Wb   = (unsigned short*)((char*)d_ws + part_bytes);

        convert_w_k<<<dim3(512), dim3(256), 0, stream>>>(W, Wb);
        score_gemm_mfma<true><<<dim3(2048), dim3(256), 0, stream>>>(enc, Wb, dec, v, partial);
        softmax_k<true><<<dim3(BATCH), dim3(256), 0, stream>>>(partial, wts);
        context_f32_k<<<dim3(BATCH * 8), dim3(256), 0, stream>>>(enc, wts, ctx);
    } else {
        float* scores = (float*)d_ws;
        hipMemsetAsync(scores, 0, scores_bytes, stream);
        score_gemm_f32<<<dim3(16384), dim3(256), 0, stream>>>(enc, W, dec, v, scores);
        softmax_k<false><<<dim3(BATCH), dim3(256), 0, stream>>>(scores, wts);
        context_f32_k<<<dim3(BATCH * 8), dim3(256), 0, stream>>>(enc, wts, ctx);
    }
}

// Round 9
// 221.447 us; speedup vs baseline: 1.7285x; 1.0018x over previous
//
#include <hip/hip_runtime.h>
#include <hip/hip_bf16.h>
#include <math.h>

#define HIDDEN 1024
#define BATCH 32
#define SEQ 2048
#define MTOT (BATCH * SEQ)   // 65536 rows
#define N_PLANES 8           // 4 n-tiles x 2 wn-waves

#define BM 128
#define BN 256
#define BK 32
#define NKS (HIDDEN / BK)    // 32 K-steps

typedef __attribute__((ext_vector_type(8))) short          bf16x8;
typedef __attribute__((ext_vector_type(8))) unsigned short ushort8;
typedef __attribute__((ext_vector_type(4))) float          f32x4;

#define GLOAD_LDS16(g, l) __builtin_amdgcn_global_load_lds( \
    (const __attribute__((address_space(1))) void*)(g),      \
    (__attribute__((address_space(3))) void*)(l), 16, 0, 0)

#define BARRIER() asm volatile("s_barrier" ::: "memory")
#define WAITL0()  asm volatile("s_waitcnt lgkmcnt(0)" ::: "memory")
#define WAITV4()  asm volatile("s_waitcnt vmcnt(4)" ::: "memory")
#define WAITV8()  asm volatile("s_waitcnt vmcnt(8)" ::: "memory")
#define WAITV0()  asm volatile("s_waitcnt vmcnt(0)" ::: "memory")
#define SCHED0()  __builtin_amdgcn_sched_barrier(0)

// tanh(x) = 1 - 2/(exp2(x*2*log2e)+1); saturates exactly via exp2 inf/0.
__device__ __forceinline__ float fast_tanh(float x) {
    float e = __builtin_amdgcn_exp2f(x * 2.8853900817779268f);
    return 1.0f - 2.0f * __builtin_amdgcn_rcpf(1.0f + e);
}

// 8x fp32 -> bf16 RNE (bit-trick, same numerics as the convert kernels)
__device__ __forceinline__ ushort8 cvt8(float4 lo, float4 hi) {
    float va[8] = {lo.x, lo.y, lo.z, lo.w, hi.x, hi.y, hi.z, hi.w};
    ushort8 r;
    #pragma unroll
    for (int j = 0; j < 8; ++j) {
        unsigned u = __float_as_uint(va[j]);
        r[j] = (unsigned short)((u + 0x7FFFu + ((u >> 16) & 1u)) >> 16);
    }
    return r;
}

// ---------------------------------------------------------------------------
// fp32 -> bf16 (RNE) conversion for W ONLY (4 MB).
// ---------------------------------------------------------------------------
__global__ __launch_bounds__(256) void convert_w_k(
    const float* __restrict__ W, unsigned short* __restrict__ Wb)
{
    const int i = blockIdx.x * blockDim.x + threadIdx.x;   // 131072 chunks
    float4 a = ((const float4*)W)[(size_t)i * 2];
    float4 b = ((const float4*)W)[(size_t)i * 2 + 1];
    *(ushort8*)&Wb[(size_t)i * 8] = cvt8(a, b);
}

// ---------------------------------------------------------------------------
// MFMA score GEMM, BM=128 x BN=256, BK=32, 4 waves, 3-buffer rotation,
// 2-phase interleave + setprio, fused A-conversion with ONE-STEP-DEFERRED
// write (fix for round-8's same-step stall):
//   loadA(t+2) issued at step t P0; cvt+ds_write at step t+1 P0 (full step
//   of latency cover); read at step t+2 P0. Single reg set (cvt reads regs
//   in-order before the next loadA overwrites them).
// Per-wave vmcnt ledger (issue order pinned by sched_barrier(0)):
//   entering step t: [A(t+1)x4, B(t+1)x4]
//   P0: W_mid=vmcnt(4) -> A(t+1) done; writeA((t+1)%3); issue A(t+2)x4,
//       Bh0(t+2)x2.  P1: issue Bh1(t+2)x2.
//   end: W_end=vmcnt(8) -> B(t+1) resident; leaves A(t+2)+B(t+2) in flight.
// Tail: t=30 W_mid=vmcnt(4), W_end=vmcnt(0); t=31 no waits.
// Race audit: writeA((t+1)%3) at t P0 vs prior readers of that buffer
// (step t-2 P0, drained by their own WAITL0 + 4 barriers earlier) and vs
// readers at t+1 P0 (writer's ds_write drained by its P0 WAITL0, then the
// end-of-step barrier publishes). Bs re-stage >= 1 barrier after last read.
// PARTIALS=true : wave-private planes partial[(nt*2+(wid&1))*MTOT + m].
// ---------------------------------------------------------------------------
template <bool PARTIALS>
__global__ __launch_bounds__(256, 2) void score_gemm_mfma(
    const float* __restrict__ enc,            // [MTOT][HIDDEN] fp32
    const unsigned short* __restrict__ Wb,    // [HIDDEN][HIDDEN] bf16 (out,in)
    const float* __restrict__ dec,            // [BATCH][HIDDEN]
    const float* __restrict__ v,              // [HIDDEN]
    float* __restrict__ outp)                 // partial[8][MTOT] or scores[MTOT]
{
    __shared__ unsigned short As[3][BM][BK];   // 24 KiB
    __shared__ unsigned short Bs[3][BN][BK];   // 48 KiB

    // XCD-grouping swizzle (bijective: 2048 blocks = 8 xcds x 256 slots)
    const int bid  = blockIdx.x;
    const int xcd  = bid & 7;
    const int slot = bid >> 3;                 // 0..255
    const int mt   = xcd * 64 + (slot >> 2);   // 0..511
    const int nt   = slot & 3;                 // 0..3
    const int m0   = mt * BM;
    const int n0   = nt * BN;

    const int tid  = threadIdx.x;
    const int wid  = tid >> 6;
    const int lane = tid & 63;
    const int wm   = (wid >> 1) * 64;          // 0 / 64
    const int wn   = (wid & 1) * 128;          // 0 / 128

    // swizzled LDS read: byte slot = ((lane>>4) ^ (lane&3)) * 16 in 64B row
    const int rowb = (lane & 15) * 64;
    const int swzb = (((lane >> 4) ^ (lane & 3)) * 16);

    // A chunks (2 per thread); global k pre-swizzled to keep LDS linear
    const int chA0  = wid * 64 + lane;
    const int chA1  = 256 + wid * 64 + lane;
    const int rowA0 = chA0 >> 2, rowA1 = chA1 >> 2;
    const float* encA0 = &enc[(size_t)(m0 + rowA0) * HIDDEN
                              + (((chA0 & 3) ^ (rowA0 & 3)) * 8)];
    const float* encA1 = &enc[(size_t)(m0 + rowA1) * HIDDEN
                              + (((chA1 & 3) ^ (rowA1 & 3)) * 8)];

    auto loadA = [&](int k0, float4& l0, float4& h0, float4& l1, float4& h1) {
        l0 = *(const float4*)(encA0 + k0);
        h0 = *(const float4*)(encA0 + k0 + 4);
        l1 = *(const float4*)(encA1 + k0);
        h1 = *(const float4*)(encA1 + k0 + 4);
    };
    auto writeA = [&](int buf, float4 l0, float4 h0, float4 l1, float4 h1) {
        *(ushort8*)((char*)&As[buf][0][0] + (size_t)chA0 * 16) = cvt8(l0, h0);
        *(ushort8*)((char*)&As[buf][0][0] + (size_t)chA1 * 16) = cvt8(l1, h1);
    };
    auto stageB = [&](int buf, int k0, int half) {
        #pragma unroll
        for (int c = 0; c < 2; ++c) {
            const int chw = (half * 2 + c) * 256 + wid * 64;
            const int ch  = chw + lane;
            const int row = ch >> 2;
            const int gk  = k0 + (((ch & 3) ^ (row & 3)) * 8);
            GLOAD_LDS16(&Wb[(size_t)(n0 + row) * HIDDEN + gk],
                        (char*)&Bs[buf][0][0] + (size_t)chw * 16);
        }
    };

    // prologue: write As[0], As[1]; stage B(0), B(1); leave B(1)x4 in flight.
    {
        float4 p0l0, p0h0, p0l1, p0h1, p1l0, p1h0, p1l1, p1h1;
        loadA(0, p0l0, p0h0, p0l1, p0h1);
        stageB(0, 0, 0);  stageB(0, 0, 1);
        loadA(BK, p1l0, p1h0, p1l1, p1h1);
        stageB(1, BK, 0); stageB(1, BK, 1);
        asm volatile("s_waitcnt vmcnt(12)" ::: "memory"); SCHED0(); // A(0) done
        writeA(0, p0l0, p0h0, p0l1, p0h1);
        WAITV4(); SCHED0();                              // A(1)+B(0) done
        writeA(1, p1l0, p1h0, p1l1, p1h1);
        WAITL0(); SCHED0();
        BARRIER();
    }

    f32x4 acc[4][8] = {};
    float4 al0, ah0, al1, ah1;   // A(t+2) fp32 in flight (one set)

    #pragma unroll 1
    for (int t = 0; t < NKS; ++t) {
        const int cur  = t % 3;
        const int nxt  = (t + 2) % 3;
        const int prv  = (t + 1) % 3;           // buffer receiving A(t+1)
        const bool more = (t + 2 < NKS);
        const int knxt = (t + 2) * BK;
        const char* Ab = (const char*)&As[cur][0][0];
        const char* Bb = (const char*)&Bs[cur][0][0];

        bf16x8 af[4], bf[8];

        // ---------------- phase 0 ----------------
        #pragma unroll
        for (int fi = 0; fi < 4; ++fi)
            af[fi] = *(const bf16x8*)(Ab + (wm + fi * 16) * 64 + rowb + swzb);
        #pragma unroll
        for (int fj = 0; fj < 4; ++fj)
            bf[fj] = *(const bf16x8*)(Bb + (wn + fj * 16) * 64 + rowb + swzb);
        if (t >= 1 && t + 1 < NKS) {
            WAITV4(); SCHED0();                 // A(t+1) regs ready (1 step old)
            writeA(prv, al0, ah0, al1, ah1);
            SCHED0();
        }
        if (more) {
            loadA(knxt, al0, ah0, al1, ah1);    // regs free: cvt already read them
            SCHED0();
            stageB(nxt, knxt, 0);
            SCHED0();
        }
        BARRIER(); WAITL0(); SCHED0();
        __builtin_amdgcn_s_setprio(1);
        #pragma unroll
        for (int fi = 0; fi < 4; ++fi)
            #pragma unroll
            for (int fj = 0; fj < 4; ++fj)
                acc[fi][fj] = __builtin_amdgcn_mfma_f32_16x16x32_bf16(
                    af[fi], bf[fj], acc[fi][fj], 0, 0, 0);
        __builtin_amdgcn_s_setprio(0);
        SCHED0();
        BARRIER();

        // ---------------- phase 1 ----------------
        #pragma unroll
        for (int fj = 4; fj < 8; ++fj)
            bf[fj] = *(const bf16x8*)(Bb + (wn + fj * 16) * 64 + rowb + swzb);
        if (more) { stageB(nxt, knxt, 1); SCHED0(); }
        BARRIER(); WAITL0(); SCHED0();
        __builtin_amdgcn_s_setprio(1);
        #pragma unroll
        for (int fi = 0; fi < 4; ++fi)
            #pragma unroll
            for (int fj = 4; fj < 8; ++fj)
                acc[fi][fj] = __builtin_amdgcn_mfma_f32_16x16x32_bf16(
                    af[fi], bf[fj], acc[fi][fj], 0, 0, 0);
        __builtin_amdgcn_s_setprio(0);
        SCHED0();
        if (more)             { WAITV8(); }     // B(t+1) resident; A/B(t+2) fly
        else if (t + 1 < NKS) { WAITV0(); }     // t=30: drain B(31)
        SCHED0();
        if (t + 1 < NKS) BARRIER();
    }

    // Epilogue. C/D layout: col = lane&15, row = (lane>>4)*4 + reg.
    const int rowgrp = lane >> 4;
    const int col    = lane & 15;
    const int b      = m0 >> 11;               // batch (block-uniform)
    const float* decb = dec + (size_t)b * HIDDEN;

    float2 dv[8];
    #pragma unroll
    for (int fj = 0; fj < 8; ++fj) {
        const int n = n0 + wn + fj * 16 + col;
        dv[fj] = make_float2(decb[n], v[n]);
    }

    const size_t plane = (size_t)(nt * 2 + (wid & 1)) * MTOT;  // wave-private

    #pragma unroll
    for (int fi = 0; fi < 4; ++fi) {
        #pragma unroll
        for (int r = 0; r < 4; ++r) {
            const int m = m0 + wm + fi * 16 + rowgrp * 4 + r;
            float rp = 0.f;
            #pragma unroll
            for (int fj = 0; fj < 8; ++fj)
                rp = fmaf(fast_tanh(acc[fi][fj][r] + dv[fj].x), dv[fj].y, rp);
            rp += __shfl_xor(rp, 1, 64);
            rp += __shfl_xor(rp, 2, 64);
            rp += __shfl_xor(rp, 4, 64);
            rp += __shfl_xor(rp, 8, 64);
            if (col == 0) {
                if (PARTIALS) outp[plane + m] = rp;
                else          atomicAdd(&outp[m], rp);
            }
        }
    }
}

// ---------------------------------------------------------------------------
// softmax over SEQ per batch. PARTIALS: sum 8 partial score planes first.
// ---------------------------------------------------------------------------
template <bool PARTIALS>
__global__ __launch_bounds__(256) void softmax_k(
    const float* __restrict__ scores, float* __restrict__ wts)
{
    __shared__ float redmax[4];
    __shared__ float redsum[4];
    const int b = blockIdx.x;
    const int tid = threadIdx.x;

    float vals[8];
    float lmax = -1e30f;
    #pragma unroll
    for (int j = 0; j < 8; ++j) {
        const int idx = b * SEQ + tid + j * 256;
        float s;
        if (PARTIALS) {
            s = 0.f;
            #pragma unroll
            for (int p = 0; p < N_PLANES; ++p)
                s += scores[(size_t)p * MTOT + idx];
        } else {
            s = scores[idx];
        }
        vals[j] = s;
        lmax = fmaxf(lmax, s);
    }
    #pragma unroll
    for (int off = 1; off < 64; off <<= 1)
        lmax = fmaxf(lmax, __shfl_xor(lmax, off, 64));
    if ((tid & 63) == 0) redmax[tid >> 6] = lmax;
    __syncthreads();
    const float gmax = fmaxf(fmaxf(redmax[0], redmax[1]),
                             fmaxf(redmax[2], redmax[3]));

    float lsum = 0.f;
    #pragma unroll
    for (int j = 0; j < 8; ++j) {
        vals[j] = expf(vals[j] - gmax);
        lsum += vals[j];
    }
    #pragma unroll
    for (int off = 1; off < 64; off <<= 1)
        lsum += __shfl_xor(lsum, off, 64);
    if ((tid & 63) == 0) redsum[tid >> 6] = lsum;
    __syncthreads();
    const float inv = 1.f / (redsum[0] + redsum[1] + redsum[2] + redsum[3]);

    #pragma unroll
    for (int j = 0; j < 8; ++j)
        wts[b * SEQ + tid + j * 256] = vals[j] * inv;
}

// ---------------------------------------------------------------------------
// context[b,h] = sum_s w[b,s] * enc[b,s,h], fp32 enc, float4 loads.
// ---------------------------------------------------------------------------
__global__ __launch_bounds__(256) void context_f32_k(
    const float* __restrict__ enc,
    const float* __restrict__ w,
    float* __restrict__ ctx)
{
    const int b     = blockIdx.x >> 3;
    const int chunk = blockIdx.x & 7;
    const int sOff  = threadIdx.x >> 5;        // 0..7
    const int quad  = threadIdx.x & 31;        // 0..31
    const int h     = chunk * 128 + quad * 4;

    float4 acc = {0.f, 0.f, 0.f, 0.f};
    #pragma unroll 4
    for (int s = sOff; s < SEQ; s += 8) {
        const float ws = w[b * SEQ + s];
        const float4 e = *(const float4*)&enc[(size_t)(b * SEQ + s) * HIDDEN + h];
        acc.x = fmaf(ws, e.x, acc.x);
        acc.y = fmaf(ws, e.y, acc.y);
        acc.z = fmaf(ws, e.z, acc.z);
        acc.w = fmaf(ws, e.w, acc.w);
    }

    __shared__ float4 red[8][32];
    red[sOff][quad] = acc;
    __syncthreads();
    if (sOff == 0) {
        float4 r = red[0][quad];
        #pragma unroll
        for (int t = 1; t < 8; ++t) {
            r.x += red[t][quad].x; r.y += red[t][quad].y;
            r.z += red[t][quad].z; r.w += red[t][quad].w;
        }
        *(float4*)&ctx[b * HIDDEN + h] = r;
    }
}

// ---------------------------------------------------------------------------
// Fallback fp32 path (no workspace beyond scores).
// ---------------------------------------------------------------------------
__global__ __launch_bounds__(256) void score_gemm_f32(
    const float* __restrict__ enc, const float* __restrict__ W,
    const float* __restrict__ dec, const float* __restrict__ v,
    float* __restrict__ scores)
{
    __shared__ float As[16][64 + 1];
    __shared__ float Bs[16][64 + 1];
    const int tid = threadIdx.x;
    const int m0 = (blockIdx.x >> 4) * 64;
    const int n0 = (blockIdx.x & 15) * 64;
    const int ty = tid >> 4, tx = tid & 15;
    const int lr = tid >> 2, lc = tid & 3;
    float acc[4][4] = {};
    for (int k0 = 0; k0 < HIDDEN; k0 += 16) {
        float4 a = *(const float4*)&enc[(size_t)(m0 + lr) * HIDDEN + k0 + lc * 4];
        float4 b = *(const float4*)&W  [(size_t)(n0 + lr) * HIDDEN + k0 + lc * 4];
        __syncthreads();
        As[lc*4+0][lr]=a.x; As[lc*4+1][lr]=a.y; As[lc*4+2][lr]=a.z; As[lc*4+3][lr]=a.w;
        Bs[lc*4+0][lr]=b.x; Bs[lc*4+1][lr]=b.y; Bs[lc*4+2][lr]=b.z; Bs[lc*4+3][lr]=b.w;
        __syncthreads();
        #pragma unroll
        for (int k = 0; k < 16; ++k) {
            float4 av = *(const float4*)&As[k][ty * 4];
            float4 bv = *(const float4*)&Bs[k][tx * 4];
            float aa[4] = {av.x, av.y, av.z, av.w};
            float bb[4] = {bv.x, bv.y, bv.z, bv.w};
            #pragma unroll
            for (int i = 0; i < 4; ++i)
                #pragma unroll
                for (int j = 0; j < 4; ++j)
                    acc[i][j] = fmaf(aa[i], bb[j], acc[i][j]);
        }
    }
    float rowpart[4];
    #pragma unroll
    for (int i = 0; i < 4; ++i) {
        const int m = m0 + ty * 4 + i;
        const int b = m >> 11;
        float rp = 0.f;
        #pragma unroll
        for (int j = 0; j < 4; ++j) {
            const int n = n0 + tx * 4 + j;
            rp = fmaf(fast_tanh(acc[i][j] + dec[b * HIDDEN + n]), v[n], rp);
        }
        rowpart[i] = rp;
    }
    #pragma unroll
    for (int off = 1; off <= 8; off <<= 1)
        #pragma unroll
        for (int i = 0; i < 4; ++i)
            rowpart[i] += __shfl_xor(rowpart[i], off, 64);
    if (tx == 0)
        #pragma unroll
        for (int i = 0; i < 4; ++i)
            atomicAdd(&scores[m0 + ty * 4 + i], rowpart[i]);
}

// ---------------------------------------------------------------------------
extern "C" void kernel_launch(void* const* d_in, const int* in_sizes, int n_in,
                              void* d_out, int out_size, void* d_ws, size_t ws_size,
                              hipStream_t stream) {
    const float* dec = (const float*)d_in[0];   // [32, 1024]
    const float* enc = (const float*)d_in[1];   // [32, 2048, 1024]
    const float* W   = (const float*)d_in[2];   // [1024, 1024]
    const float* v   = (const float*)d_in[3];   // [1, 1024]

    float* out = (float*)d_out;
    float* ctx = out;                           // [32, 1024]
    float* wts = out + BATCH * HIDDEN;          // [32, 2048]

    const size_t part_bytes   = (size_t)N_PLANES * MTOT * sizeof(float); // 2 MiB
    const size_t wb_bytes     = (size_t)HIDDEN * HIDDEN * 2;             // 2 MiB
    const size_t scores_bytes = (size_t)MTOT * sizeof(float);            // 256 KiB
    const size_t need = part_bytes + wb_bytes;                           // 4 MiB

    if (ws_size >= need) {
        float* partial       = (float*)d_ws;
        unsigned short* Wb   = (unsigned short*)((char*)d_ws + part_bytes);

        convert_w_k<<<dim3(512), dim3(256), 0, stream>>>(W, Wb);
        score_gemm_mfma<true><<<dim3(2048), dim3(256), 0, stream>>>(enc, Wb, dec, v, partial);
        softmax_k<true><<<dim3(BATCH), dim3(256), 0, stream>>>(partial, wts);
        context_f32_k<<<dim3(BATCH * 8), dim3(256), 0, stream>>>(enc, wts, ctx);
    } else {
        float* scores = (float*)d_ws;
        hipMemsetAsync(scores, 0, scores_bytes, stream);
        score_gemm_f32<<<dim3(16384), dim3(256), 0, stream>>>(enc, W, dec, v, scores);
        softmax_k<false><<<dim3(BATCH), dim3(256), 0, stream>>>(scores, wts);
        context_f32_k<<<dim3(BATCH * 8), dim3(256), 0, stream>>>(enc, wts, ctx);
    }
}

// Round 10
// 208.124 us; speedup vs baseline: 1.8391x; 1.0640x over previous
//
#include <hip/hip_runtime.h>
#include <hip/hip_bf16.h>
#include <math.h>

#define HIDDEN 1024
#define BATCH 32
#define SEQ 2048
#define MTOT (BATCH * SEQ)   // 65536 rows
#define N_PLANES 8           // 4 n-tiles x 2 wn-waves

#define BM 128
#define BN 256
#define BK 32
#define NKS (HIDDEN / BK)    // 32 K-steps

typedef __attribute__((ext_vector_type(8))) short          bf16x8;
typedef __attribute__((ext_vector_type(8))) unsigned short ushort8;
typedef __attribute__((ext_vector_type(4))) float          f32x4;

#define GLOAD_LDS16(g, l) __builtin_amdgcn_global_load_lds( \
    (const __attribute__((address_space(1))) void*)(g),      \
    (__attribute__((address_space(3))) void*)(l), 16, 0, 0)

#define BARRIER() asm volatile("s_barrier" ::: "memory")
#define WAITL0()  asm volatile("s_waitcnt lgkmcnt(0)" ::: "memory")
#define WAITL6()  asm volatile("s_waitcnt lgkmcnt(6)" ::: "memory")
#define WAITV4()  asm volatile("s_waitcnt vmcnt(4)" ::: "memory")
#define WAITV8()  asm volatile("s_waitcnt vmcnt(8)" ::: "memory")
#define WAITV0()  asm volatile("s_waitcnt vmcnt(0)" ::: "memory")
#define SCHED0()  __builtin_amdgcn_sched_barrier(0)

// tanh(x) = 1 - 2/(exp2(x*2*log2e)+1); saturates exactly via exp2 inf/0.
__device__ __forceinline__ float fast_tanh(float x) {
    float e = __builtin_amdgcn_exp2f(x * 2.8853900817779268f);
    return 1.0f - 2.0f * __builtin_amdgcn_rcpf(1.0f + e);
}

// 8x fp32 -> bf16 RNE (bit-trick, same numerics as the convert kernels)
__device__ __forceinline__ ushort8 cvt8(float4 lo, float4 hi) {
    float va[8] = {lo.x, lo.y, lo.z, lo.w, hi.x, hi.y, hi.z, hi.w};
    ushort8 r;
    #pragma unroll
    for (int j = 0; j < 8; ++j) {
        unsigned u = __float_as_uint(va[j]);
        r[j] = (unsigned short)((u + 0x7FFFu + ((u >> 16) & 1u)) >> 16);
    }
    return r;
}

// ---------------------------------------------------------------------------
// fp32 -> bf16 (RNE) conversion for W ONLY (4 MB).
// ---------------------------------------------------------------------------
__global__ __launch_bounds__(256) void convert_w_k(
    const float* __restrict__ W, unsigned short* __restrict__ Wb)
{
    const int i = blockIdx.x * blockDim.x + threadIdx.x;   // 131072 chunks
    float4 a = ((const float4*)W)[(size_t)i * 2];
    float4 b = ((const float4*)W)[(size_t)i * 2 + 1];
    *(ushort8*)&Wb[(size_t)i * 8] = cvt8(a, b);
}

// ---------------------------------------------------------------------------
// MFMA score GEMM, BM=128 x BN=256, BK=32, 4 waves, 3-buffer rotation,
// fused A-conversion (1-step-deferred write), SINGLE BARRIER PER K-STEP.
//
// Hazard audit (why 1 barrier suffices):
//  - Within step t: reads touch only buf cur=t%3; writeA targets (t+1)%3;
//    stageB/loadA target (t+2)%3 — disjoint by rotation.
//  - As[(t+1)%3] write (step t) vs its prior readers (step t-2, as cur):
//    reader's own WAITL* (pre-MFMA, step t-2) + end-of-(t-2),(t-1) barriers.
//  - Bs[(t+2)%3] re-stage (step t) vs prior readers (step t-1): reader's own
//    WAITL0 (step t-1) + end-of-(t-1) barrier.
//  - Publication of As[t+1]/Bs[t+1] for step t+1: writer's ds_writes drain
//    at its lgkmcnt(0) (pre-MFMA2); B staging retired by WAITV8; then the
//    single end-of-step barrier publishes both.
// vmcnt ledger (issue order pinned by SCHED0):
//  entering t: [A(t+1)x4, B(t+1)x4]. WAITV4 -> A(t+1) done -> writeA.
//  issue A(t+2)x4 + B(t+2)x4. WAITV8 (post-MFMA) -> B(t+1) resident,
//  leaves A/B(t+2) in flight. Tails: t=30 WAITV0; t=31 none.
// lgkm split: 12 ds_read + 2 ds_write in queue; WAITL6 -> first 8 reads
// (af0-3,bf0-3) ready -> MFMA cluster 1 overlaps bf4-7 + writes draining;
// WAITL0 -> MFMA cluster 2 (also drains writeA before the barrier).
// PARTIALS=true : wave-private planes partial[(nt*2+(wid&1))*MTOT + m].
// ---------------------------------------------------------------------------
template <bool PARTIALS>
__global__ __launch_bounds__(256, 2) void score_gemm_mfma(
    const float* __restrict__ enc,            // [MTOT][HIDDEN] fp32
    const unsigned short* __restrict__ Wb,    // [HIDDEN][HIDDEN] bf16 (out,in)
    const float* __restrict__ dec,            // [BATCH][HIDDEN]
    const float* __restrict__ v,              // [HIDDEN]
    float* __restrict__ outp)                 // partial[8][MTOT] or scores[MTOT]
{
    __shared__ unsigned short As[3][BM][BK];   // 24 KiB
    __shared__ unsigned short Bs[3][BN][BK];   // 48 KiB

    // XCD-grouping swizzle (bijective: 2048 blocks = 8 xcds x 256 slots)
    const int bid  = blockIdx.x;
    const int xcd  = bid & 7;
    const int slot = bid >> 3;                 // 0..255
    const int mt   = xcd * 64 + (slot >> 2);   // 0..511
    const int nt   = slot & 3;                 // 0..3
    const int m0   = mt * BM;
    const int n0   = nt * BN;

    const int tid  = threadIdx.x;
    const int wid  = tid >> 6;
    const int lane = tid & 63;
    const int wm   = (wid >> 1) * 64;          // 0 / 64
    const int wn   = (wid & 1) * 128;          // 0 / 128

    // LDS read address (16B slot q = lane>>4 within the 64B k-row)
    const int rowb = (lane & 15) * 64;
    const int swzb = (((lane >> 4) ^ (lane & 3)) * 16);

    // A chunks (2 per thread); global k pre-swizzled to keep LDS linear
    const int chA0  = wid * 64 + lane;
    const int chA1  = 256 + wid * 64 + lane;
    const int rowA0 = chA0 >> 2, rowA1 = chA1 >> 2;
    const float* encA0 = &enc[(size_t)(m0 + rowA0) * HIDDEN
                              + (((chA0 & 3) ^ (rowA0 & 3)) * 8)];
    const float* encA1 = &enc[(size_t)(m0 + rowA1) * HIDDEN
                              + (((chA1 & 3) ^ (rowA1 & 3)) * 8)];

    auto loadA = [&](int k0, float4& l0, float4& h0, float4& l1, float4& h1) {
        l0 = *(const float4*)(encA0 + k0);
        h0 = *(const float4*)(encA0 + k0 + 4);
        l1 = *(const float4*)(encA1 + k0);
        h1 = *(const float4*)(encA1 + k0 + 4);
    };
    auto writeA = [&](int buf, float4 l0, float4 h0, float4 l1, float4 h1) {
        *(ushort8*)((char*)&As[buf][0][0] + (size_t)chA0 * 16) = cvt8(l0, h0);
        *(ushort8*)((char*)&As[buf][0][0] + (size_t)chA1 * 16) = cvt8(l1, h1);
    };
    auto stageB = [&](int buf, int k0) {
        #pragma unroll
        for (int c = 0; c < 4; ++c) {
            const int chw = c * 256 + wid * 64;
            const int ch  = chw + lane;
            const int row = ch >> 2;
            const int gk  = k0 + (((ch & 3) ^ (row & 3)) * 8);
            GLOAD_LDS16(&Wb[(size_t)(n0 + row) * HIDDEN + gk],
                        (char*)&Bs[buf][0][0] + (size_t)chw * 16);
        }
    };

    // prologue: write As[0], As[1]; stage B(0), B(1); leave B(1)x4 in flight.
    {
        float4 p0l0, p0h0, p0l1, p0h1, p1l0, p1h0, p1l1, p1h1;
        loadA(0, p0l0, p0h0, p0l1, p0h1);
        stageB(0, 0);
        loadA(BK, p1l0, p1h0, p1l1, p1h1);
        stageB(1, BK);
        asm volatile("s_waitcnt vmcnt(12)" ::: "memory"); SCHED0(); // A(0) done
        writeA(0, p0l0, p0h0, p0l1, p0h1);
        WAITV4(); SCHED0();                              // A(1)+B(0) done
        writeA(1, p1l0, p1h0, p1l1, p1h1);
        WAITL0(); SCHED0();
        BARRIER();
    }

    f32x4 acc[4][8] = {};
    float4 al0, ah0, al1, ah1;   // A(t+2) fp32 in flight (one set)

    #pragma unroll 1
    for (int t = 0; t < NKS; ++t) {
        const int cur  = t % 3;
        const int nxt  = (t + 2) % 3;
        const int prv  = (t + 1) % 3;           // buffer receiving A(t+1)
        const bool more = (t + 2 < NKS);
        const int knxt = (t + 2) * BK;
        const char* Ab = (const char*)&As[cur][0][0];
        const char* Bb = (const char*)&Bs[cur][0][0];

        bf16x8 af[4], bf[8];

        // issue all 12 ds_reads of buf cur (af0-3, bf0-3, bf4-7 in order)
        #pragma unroll
        for (int fi = 0; fi < 4; ++fi)
            af[fi] = *(const bf16x8*)(Ab + (wm + fi * 16) * 64 + rowb + swzb);
        #pragma unroll
        for (int fj = 0; fj < 8; ++fj)
            bf[fj] = *(const bf16x8*)(Bb + (wn + fj * 16) * 64 + rowb + swzb);
        SCHED0();

        // retire A(t+1) fp32 loads; convert + ds_write into As[prv]
        if (t >= 1 && t + 1 < NKS) {
            WAITV4(); SCHED0();
            writeA(prv, al0, ah0, al1, ah1);
            SCHED0();
        }
        // issue next prefetch (A then B — ledger order)
        if (more) {
            loadA(knxt, al0, ah0, al1, ah1);
            SCHED0();
            stageB(nxt, knxt);
            SCHED0();
        }

        // MFMA cluster 1: needs af0-3 + bf0-3 (first 8 ds_reads)
        WAITL6(); SCHED0();
        __builtin_amdgcn_s_setprio(1);
        #pragma unroll
        for (int fi = 0; fi < 4; ++fi)
            #pragma unroll
            for (int fj = 0; fj < 4; ++fj)
                acc[fi][fj] = __builtin_amdgcn_mfma_f32_16x16x32_bf16(
                    af[fi], bf[fj], acc[fi][fj], 0, 0, 0);
        __builtin_amdgcn_s_setprio(0);
        SCHED0();

        // MFMA cluster 2: needs bf4-7 (drains everything incl. writeA)
        WAITL0(); SCHED0();
        __builtin_amdgcn_s_setprio(1);
        #pragma unroll
        for (int fi = 0; fi < 4; ++fi)
            #pragma unroll
            for (int fj = 4; fj < 8; ++fj)
                acc[fi][fj] = __builtin_amdgcn_mfma_f32_16x16x32_bf16(
                    af[fi], bf[fj], acc[fi][fj], 0, 0, 0);
        __builtin_amdgcn_s_setprio(0);
        SCHED0();

        // retire B(t+1) (leave A/B(t+2) in flight); publish; next step
        if (more)             { WAITV8(); }
        else if (t + 1 < NKS) { WAITV0(); }     // t=30: drain B(31)
        SCHED0();
        if (t + 1 < NKS) BARRIER();
    }

    // Epilogue. C/D layout: col = lane&15, row = (lane>>4)*4 + reg.
    const int rowgrp = lane >> 4;
    const int col    = lane & 15;
    const int b      = m0 >> 11;               // batch (block-uniform)
    const float* decb = dec + (size_t)b * HIDDEN;

    float2 dv[8];
    #pragma unroll
    for (int fj = 0; fj < 8; ++fj) {
        const int n = n0 + wn + fj * 16 + col;
        dv[fj] = make_float2(decb[n], v[n]);
    }

    const size_t plane = (size_t)(nt * 2 + (wid & 1)) * MTOT;  // wave-private

    #pragma unroll
    for (int fi = 0; fi < 4; ++fi) {
        #pragma unroll
        for (int r = 0; r < 4; ++r) {
            const int m = m0 + wm + fi * 16 + rowgrp * 4 + r;
            float rp = 0.f;
            #pragma unroll
            for (int fj = 0; fj < 8; ++fj)
                rp = fmaf(fast_tanh(acc[fi][fj][r] + dv[fj].x), dv[fj].y, rp);
            rp += __shfl_xor(rp, 1, 64);
            rp += __shfl_xor(rp, 2, 64);
            rp += __shfl_xor(rp, 4, 64);
            rp += __shfl_xor(rp, 8, 64);
            if (col == 0) {
                if (PARTIALS) outp[plane + m] = rp;
                else          atomicAdd(&outp[m], rp);
            }
        }
    }
}

// ---------------------------------------------------------------------------
// softmax over SEQ per batch. PARTIALS: sum 8 partial score planes first.
// ---------------------------------------------------------------------------
template <bool PARTIALS>
__global__ __launch_bounds__(256) void softmax_k(
    const float* __restrict__ scores, float* __restrict__ wts)
{
    __shared__ float redmax[4];
    __shared__ float redsum[4];
    const int b = blockIdx.x;
    const int tid = threadIdx.x;

    float vals[8];
    float lmax = -1e30f;
    #pragma unroll
    for (int j = 0; j < 8; ++j) {
        const int idx = b * SEQ + tid + j * 256;
        float s;
        if (PARTIALS) {
            s = 0.f;
            #pragma unroll
            for (int p = 0; p < N_PLANES; ++p)
                s += scores[(size_t)p * MTOT + idx];
        } else {
            s = scores[idx];
        }
        vals[j] = s;
        lmax = fmaxf(lmax, s);
    }
    #pragma unroll
    for (int off = 1; off < 64; off <<= 1)
        lmax = fmaxf(lmax, __shfl_xor(lmax, off, 64));
    if ((tid & 63) == 0) redmax[tid >> 6] = lmax;
    __syncthreads();
    const float gmax = fmaxf(fmaxf(redmax[0], redmax[1]),
                             fmaxf(redmax[2], redmax[3]));

    float lsum = 0.f;
    #pragma unroll
    for (int j = 0; j < 8; ++j) {
        vals[j] = expf(vals[j] - gmax);
        lsum += vals[j];
    }
    #pragma unroll
    for (int off = 1; off < 64; off <<= 1)
        lsum += __shfl_xor(lsum, off, 64);
    if ((tid & 63) == 0) redsum[tid >> 6] = lsum;
    __syncthreads();
    const float inv = 1.f / (redsum[0] + redsum[1] + redsum[2] + redsum[3]);

    #pragma unroll
    for (int j = 0; j < 8; ++j)
        wts[b * SEQ + tid + j * 256] = vals[j] * inv;
}

// ---------------------------------------------------------------------------
// context[b,h] = sum_s w[b,s] * enc[b,s,h], fp32 enc, float4 loads.
// ---------------------------------------------------------------------------
__global__ __launch_bounds__(256) void context_f32_k(
    const float* __restrict__ enc,
    const float* __restrict__ w,
    float* __restrict__ ctx)
{
    const int b     = blockIdx.x >> 3;
    const int chunk = blockIdx.x & 7;
    const int sOff  = threadIdx.x >> 5;        // 0..7
    const int quad  = threadIdx.x & 31;        // 0..31
    const int h     = chunk * 128 + quad * 4;

    float4 acc = {0.f, 0.f, 0.f, 0.f};
    #pragma unroll 4
    for (int s = sOff; s < SEQ; s += 8) {
        const float ws = w[b * SEQ + s];
        const float4 e = *(const float4*)&enc[(size_t)(b * SEQ + s) * HIDDEN + h];
        acc.x = fmaf(ws, e.x, acc.x);
        acc.y = fmaf(ws, e.y, acc.y);
        acc.z = fmaf(ws, e.z, acc.z);
        acc.w = fmaf(ws, e.w, acc.w);
    }

    __shared__ float4 red[8][32];
    red[sOff][quad] = acc;
    __syncthreads();
    if (sOff == 0) {
        float4 r = red[0][quad];
        #pragma unroll
        for (int t = 1; t < 8; ++t) {
            r.x += red[t][quad].x; r.y += red[t][quad].y;
            r.z += red[t][quad].z; r.w += red[t][quad].w;
        }
        *(float4*)&ctx[b * HIDDEN + h] = r;
    }
}

// ---------------------------------------------------------------------------
// Fallback fp32 path (no workspace beyond scores).
// ---------------------------------------------------------------------------
__global__ __launch_bounds__(256) void score_gemm_f32(
    const float* __restrict__ enc, const float* __restrict__ W,
    const float* __restrict__ dec, const float* __restrict__ v,
    float* __restrict__ scores)
{
    __shared__ float As[16][64 + 1];
    __shared__ float Bs[16][64 + 1];
    const int tid = threadIdx.x;
    const int m0 = (blockIdx.x >> 4) * 64;
    const int n0 = (blockIdx.x & 15) * 64;
    const int ty = tid >> 4, tx = tid & 15;
    const int lr = tid >> 2, lc = tid & 3;
    float acc[4][4] = {};
    for (int k0 = 0; k0 < HIDDEN; k0 += 16) {
        float4 a = *(const float4*)&enc[(size_t)(m0 + lr) * HIDDEN + k0 + lc * 4];
        float4 b = *(const float4*)&W  [(size_t)(n0 + lr) * HIDDEN + k0 + lc * 4];
        __syncthreads();
        As[lc*4+0][lr]=a.x; As[lc*4+1][lr]=a.y; As[lc*4+2][lr]=a.z; As[lc*4+3][lr]=a.w;
        Bs[lc*4+0][lr]=b.x; Bs[lc*4+1][lr]=b.y; Bs[lc*4+2][lr]=b.z; Bs[lc*4+3][lr]=b.w;
        __syncthreads();
        #pragma unroll
        for (int k = 0; k < 16; ++k) {
            float4 av = *(const float4*)&As[k][ty * 4];
            float4 bv = *(const float4*)&Bs[k][tx * 4];
            float aa[4] = {av.x, av.y, av.z, av.w};
            float bb[4] = {bv.x, bv.y, bv.z, bv.w};
            #pragma unroll
            for (int i = 0; i < 4; ++i)
                #pragma unroll
                for (int j = 0; j < 4; ++j)
                    acc[i][j] = fmaf(aa[i], bb[j], acc[i][j]);
        }
    }
    float rowpart[4];
    #pragma unroll
    for (int i = 0; i < 4; ++i) {
        const int m = m0 + ty * 4 + i;
        const int b = m >> 11;
        float rp = 0.f;
        #pragma unroll
        for (int j = 0; j < 4; ++j) {
            const int n = n0 + tx * 4 + j;
            rp = fmaf(fast_tanh(acc[i][j] + dec[b * HIDDEN + n]), v[n], rp);
        }
        rowpart[i] = rp;
    }
    #pragma unroll
    for (int off = 1; off <= 8; off <<= 1)
        #pragma unroll
        for (int i = 0; i < 4; ++i)
            rowpart[i] += __shfl_xor(rowpart[i], off, 64);
    if (tx == 0)
        #pragma unroll
        for (int i = 0; i < 4; ++i)
            atomicAdd(&scores[m0 + ty * 4 + i], rowpart[i]);
}

// ---------------------------------------------------------------------------
extern "C" void kernel_launch(void* const* d_in, const int* in_sizes, int n_in,
                              void* d_out, int out_size, void* d_ws, size_t ws_size,
                              hipStream_t stream) {
    const float* dec = (const float*)d_in[0];   // [32, 1024]
    const float* enc = (const float*)d_in[1];   // [32, 2048, 1024]
    const float* W   = (const float*)d_in[2];   // [1024, 1024]
    const float* v   = (const float*)d_in[3];   // [1, 1024]

    float* out = (float*)d_out;
    float* ctx = out;                           // [32, 1024]
    float* wts = out + BATCH * HIDDEN;          // [32, 2048]

    const size_t part_bytes   = (size_t)N_PLANES * MTOT * sizeof(float); // 2 MiB
    const size_t wb_bytes     = (size_t)HIDDEN * HIDDEN * 2;             // 2 MiB
    const size_t scores_bytes = (size_t)MTOT * sizeof(float);            // 256 KiB
    const size_t need = part_bytes + wb_bytes;                           // 4 MiB

    if (ws_size >= need) {
        float* partial       = (float*)d_ws;
        unsigned short* Wb   = (unsigned short*)((char*)d_ws + part_bytes);

        convert_w_k<<<dim3(512), dim3(256), 0, stream>>>(W, Wb);
        score_gemm_mfma<true><<<dim3(2048), dim3(256), 0, stream>>>(enc, Wb, dec, v, partial);
        softmax_k<true><<<dim3(BATCH), dim3(256), 0, stream>>>(partial, wts);
        context_f32_k<<<dim3(BATCH * 8), dim3(256), 0, stream>>>(enc, wts, ctx);
    } else {
        float* scores = (float*)d_ws;
        hipMemsetAsync(scores, 0, scores_bytes, stream);
        score_gemm_f32<<<dim3(16384), dim3(256), 0, stream>>>(enc, W, dec, v, scores);
        softmax_k<false><<<dim3(BATCH), dim3(256), 0, stream>>>(scores, wts);
        context_f32_k<<<dim3(BATCH * 8), dim3(256), 0, stream>>>(enc, wts, ctx);
    }
}